// Round 10
// baseline (322.586 us; speedup 1.0000x reference)
//
#include <hip/hip_runtime.h>
#include <hip/hip_bf16.h>

#define BB 4
#define SS 2048
#define DD 1024
#define HH 16
#define DHH 64

typedef __attribute__((ext_vector_type(8))) short short8;
typedef __attribute__((ext_vector_type(4))) float floatx4;
typedef __attribute__((ext_vector_type(16))) float floatx16;
typedef __attribute__((ext_vector_type(4))) int int4v;

__device__ inline short f2bf(float x) {
  union { float f; unsigned u; } v; v.f = x;
  unsigned r = v.u + 0x7FFFu + ((v.u >> 16) & 1u);
  return (short)(r >> 16);
}
__device__ inline float bf2f(short x) {
  union { unsigned u; float f; } v;
  v.u = ((unsigned)(unsigned short)x) << 16;
  return v.f;
}
__device__ inline int cvtpk(float lo, float hi) {
  int r;
  asm("v_cvt_pk_bf16_f32 %0, %1, %2" : "=v"(r) : "v"(lo), "v"(hi));
  return r;
}
// DST[63:32] <-> SRC[31:0]
__device__ inline void pl32swap(int& a, int& b) {
  asm("v_permlane32_swap_b32 %0, %1" : "+v"(a), "+v"(b));
}

typedef __attribute__((address_space(1))) const unsigned int GUI;
typedef __attribute__((address_space(3))) unsigned int LUI;
__device__ inline void gload16(const void* g, void* l) {
  __builtin_amdgcn_global_load_lds((GUI*)g, (LUI*)l, 16, 0, 0);
}

// ---------------- f32 -> bf16 conversion ----------------
__global__ __launch_bounds__(256) void cvt_kernel(const float* __restrict__ in,
                                                  short* __restrict__ out, int n4,
                                                  float scale) {
  int i = blockIdx.x * 256 + threadIdx.x;
  if (i >= n4) return;
  float4 v = ((const float4*)in)[i];
  short4 o;
  o.x = f2bf(v.x * scale); o.y = f2bf(v.y * scale);
  o.z = f2bf(v.z * scale); o.w = f2bf(v.w * scale);
  ((short4*)out)[i] = o;
}

// ---------------- weight transpose + convert (+scale) ----------------
__global__ __launch_bounds__(256) void wtrans_kernel(const float* __restrict__ in,
                                                     short* __restrict__ out, float scale) {
  __shared__ float tile[16][17];
  int tx = threadIdx.x & 15, ty = threadIdx.x >> 4;
  int k = blockIdx.y * 16 + ty;
  int n = blockIdx.x * 16 + tx;
  tile[ty][tx] = in[(size_t)k * 1024 + n];
  __syncthreads();
  int n2 = blockIdx.x * 16 + ty;
  int k2 = blockIdx.y * 16 + tx;
  out[(size_t)n2 * 1024 + k2] = f2bf(tile[tx][ty] * scale);
}

// ---------------- bias -> blocked bf16 layout (32-kv tiles) -------------------
// out[((b*64 + kv32)*8 + s)*8192 + q*4 + j] = bias[b][q][kv32*32 + 8g+4hi+j]*scale
// where s = g*2 + hi (g in 0..3, hi in 0..1).
__global__ __launch_bounds__(256) void btrans_blk(const float* __restrict__ in,
                                                  short* __restrict__ out, float scale) {
  __shared__ short tile[64][68];
  const int t = threadIdx.x;
  const int b = blockIdx.z;
  const int q0 = blockIdx.x * 64, kv0 = blockIdx.y * 64;
  const float* gin = in + ((size_t)b * SS + q0) * SS + kv0;
#pragma unroll
  for (int i = 0; i < 4; ++i) {
    int idx = t + 256 * i;
    int row = idx >> 4, c4 = idx & 15;
    float4 v = ((const float4*)(gin + (size_t)row * SS))[c4];
    tile[row][c4 * 4 + 0] = f2bf(v.x * scale);
    tile[row][c4 * 4 + 1] = f2bf(v.y * scale);
    tile[row][c4 * 4 + 2] = f2bf(v.z * scale);
    tile[row][c4 * 4 + 3] = f2bf(v.w * scale);
  }
  __syncthreads();
  short* gout = out + ((size_t)(b * 64 + (kv0 >> 5)) * 8) * 8192 + (size_t)q0 * 4;
#pragma unroll
  for (int i = 0; i < 4; ++i) {
    int idx = t + 256 * i;
    int s = idx >> 6, ql = idx & 63;       // s in 0..15 spans two 32-kv tiles
    int kvt = s >> 3, s7 = s & 7;          // kvt: which 32-tile; s7 = g*2+hi
    int g = s7 >> 1, hi = s7 & 1;
    short4 v = *(const short4*)&tile[ql][kvt * 32 + g * 8 + hi * 4];
    *(short4*)&gout[((size_t)kvt * 8 + s7) * 8192 + (size_t)ql * 4] = v;
  }
}

// ---------------- V transpose: [B][S][ldin] cols 0..1023 -> [B][1024][S] --------
__global__ __launch_bounds__(256) void vtrans_kernel(const short* __restrict__ in,
                                                     short* __restrict__ out, int ldin) {
  __shared__ int tile[64][33];
  const int t = threadIdx.x;
  const int b = blockIdx.z;
  const int s0 = blockIdx.x * 64, d0 = blockIdx.y * 64;
  const int* gin = (const int*)(in + (size_t)b * SS * ldin);
  const int ldi2 = ldin >> 1;
  int* gout = (int*)(out + (size_t)b * DD * SS);
#pragma unroll
  for (int i = 0; i < 8; ++i) {
    int idx = t + i * 256;
    int row = idx >> 5, col = idx & 31;
    tile[row][col] = gin[(size_t)(s0 + row) * ldi2 + (d0 >> 1) + col];
  }
  __syncthreads();
#pragma unroll
  for (int i = 0; i < 8; ++i) {
    int idx = t + i * 256;
    int d = idx >> 5, spc = idx & 31;
    int a = tile[2 * spc][d >> 1];
    int c = tile[2 * spc + 1][d >> 1];
    int o = (d & 1) ? (((a >> 16) & 0xffff) | (c & 0xffff0000))
                    : ((a & 0xffff) | (c << 16));
    gout[(size_t)(d0 + d) * (SS / 2) + (s0 >> 1) + spc] = o;
  }
}

// ---------------- bf16 MFMA GEMM, dbuf 2-phase, XCD-swizzled, T2 LDS swizzle ----
template<int OUT_F32>
__global__ __launch_bounds__(256) void gemm_kernel(const short* __restrict__ A,
                                                   const short* __restrict__ Bt,
                                                   void* __restrict__ Cout,
                                                   int M, int N, int K) {
  __shared__ alignas(16) short As[2][128][32];
  __shared__ alignas(16) short Bs[2][128][32];
  const int t = threadIdx.x;
  const int lane = t & 63, wave = t >> 6;
  const int wr = wave >> 1, wc = wave & 1;
  const int l15 = lane & 15, l4 = lane >> 4;

  const int hw = blockIdx.x;
  const int L = (hw & 7) * ((int)gridDim.x >> 3) + (hw >> 3);
  const int NY = N >> 7;
  const int bxm = L / NY, byn = L % NY;

  floatx4 acc[4][4];
#pragma unroll
  for (int i = 0; i < 4; ++i)
#pragma unroll
    for (int j = 0; j < 4; ++j) acc[i][j] = (floatx4){0.f, 0.f, 0.f, 0.f};

  const short* Ag = A + (size_t)bxm * 128 * K;
  const short* Bg = Bt + (size_t)byn * 128 * K;
  const int o0 = t * 16, o1 = t * 16 + 4096;
  const int r0 = o0 >> 6, r1 = o1 >> 6;
  const int c0 = (((o0 >> 1) & 31) ^ ((r0 & 3) << 3));
  const int c1 = (((o1 >> 1) & 31) ^ ((r1 & 3) << 3));
  const int rbase = wr * 64 + l15;
  const int cbase = wc * 64 + l15;
  const int koff = (l4 ^ (l15 & 3)) * 8;

#define GSTAGE(buf, k0)                                                  \
  gload16(&Ag[(size_t)r0 * K + (k0) + c0], (char*)As[buf] + o0);         \
  gload16(&Bg[(size_t)r0 * K + (k0) + c0], (char*)Bs[buf] + o0);         \
  gload16(&Ag[(size_t)r1 * K + (k0) + c1], (char*)As[buf] + o1);         \
  gload16(&Bg[(size_t)r1 * K + (k0) + c1], (char*)Bs[buf] + o1);

  GSTAGE(0, 0)
  __syncthreads();
  int cur = 0;
  for (int k0 = 0; k0 < K; k0 += 32) {
    if (k0 + 32 < K) { GSTAGE(cur ^ 1, k0 + 32) }
    short8 af[4], bfr[4];
#pragma unroll
    for (int mi = 0; mi < 4; ++mi) af[mi] = *(const short8*)&As[cur][rbase + mi * 16][koff];
#pragma unroll
    for (int ni = 0; ni < 4; ++ni) bfr[ni] = *(const short8*)&Bs[cur][cbase + ni * 16][koff];
    __builtin_amdgcn_s_setprio(1);
#pragma unroll
    for (int mi = 0; mi < 4; ++mi)
#pragma unroll
      for (int ni = 0; ni < 4; ++ni)
        acc[mi][ni] = __builtin_amdgcn_mfma_f32_16x16x32_bf16(af[mi], bfr[ni], acc[mi][ni], 0, 0, 0);
    __builtin_amdgcn_s_setprio(0);
    __syncthreads();
    cur ^= 1;
  }
#undef GSTAGE

  const int row0 = bxm * 128 + wr * 64 + l4 * 4;
  const int col0 = byn * 128 + wc * 64 + l15;
  if (OUT_F32) {
    float* Cf = (float*)Cout;
#pragma unroll
    for (int mi = 0; mi < 4; ++mi)
#pragma unroll
      for (int ni = 0; ni < 4; ++ni)
#pragma unroll
        for (int r = 0; r < 4; ++r)
          Cf[(size_t)(row0 + mi * 16 + r) * N + col0 + ni * 16] = acc[mi][ni][r];
  } else {
    short* Cs = (short*)Cout;
#pragma unroll
    for (int mi = 0; mi < 4; ++mi)
#pragma unroll
      for (int ni = 0; ni < 4; ++ni)
#pragma unroll
        for (int r = 0; r < 4; ++r)
          Cs[(size_t)(row0 + mi * 16 + r) * N + col0 + ni * 16] = f2bf(acc[mi][ni][r]);
  }
}

// ---------------- flash attention: KVBLK=32, 32KB LDS, no-max log2 softmax -----
// 1-D grid 1024, XCD-chunked. 4 waves x 32 q. 64 iters of 32 kv, full dbuf.
__global__ __launch_bounds__(256) void attn_kernel(const short* __restrict__ Q,
                                                   const short* __restrict__ K,
                                                   const short* __restrict__ VT,
                                                   const short* __restrict__ bias_blk,
                                                   short* __restrict__ O, int ldk) {
  __shared__ alignas(16) short Klds[2][32][64];     // 8KB
  __shared__ alignas(16) short Vtl[2][64][32];      // 8KB
  __shared__ alignas(16) short Blds[2][8][128][4];  // 16KB blocked bias

  const int t = threadIdx.x;
  const int lane = t & 63, wave = t >> 6;
  const int hw = blockIdx.x;
  const int L = (hw & 7) * 128 + (hw >> 3);
  const int bh = L >> 4;
  const int q0 = (L & 15) * 128;
  const int b = bh >> 4, h = bh & 15;
  const int l31 = lane & 31, hi = lane >> 5;

  const short* Qb = Q + (size_t)b * SS * DD + h * DHH;
  const short* Kb = K + (size_t)b * SS * ldk + h * DHH;
  const short* VTb = VT + ((size_t)b * DD + h * DHH) * SS;
  const short* Bl = bias_blk + (size_t)(b * 64) * 8 * 8192 + (size_t)q0 * 4;

  // staging geometry (one gload16 each for K and V, two for bias)
  const int krow = t >> 3, kcol = ((t & 7) ^ ((t >> 3) & 7)) * 8;
  const int vrow = t >> 2, vcol = ((t & 3) ^ ((t >> 2) & 3)) * 8;

#define STAGE_KV(buf, kvb)                                                              \
  {                                                                                     \
    gload16(&Kb[(size_t)((kvb) + krow) * ldk + kcol], (char*)&Klds[buf][0][0] + t * 16);\
    gload16(&VTb[(size_t)vrow * SS + (kvb) + vcol], (char*)&Vtl[buf][0][0] + t * 16);   \
  }
#define STAGE_B(buf, t32)                                                               \
  {                                                                                     \
    const short* bsrc = Bl + (size_t)(t32) * 8 * 8192;                                  \
    gload16(&bsrc[(size_t)(t >> 6) * 8192 + (t & 63) * 8],                              \
            (char*)&Blds[buf][0][0][0] + t * 16);                                       \
    gload16(&bsrc[(size_t)((t >> 6) + 4) * 8192 + (t & 63) * 8],                        \
            (char*)&Blds[buf][0][0][0] + 4096 + t * 16);                                \
  }

  // prologue: stage tile 0
  STAGE_KV(0, 0)
  STAGE_B(0, 0)

  const int q = wave * 32 + l31;
  short8 qf[4];
  {
    int qrow = q0 + q;
#pragma unroll
    for (int dc = 0; dc < 4; ++dc)
      qf[dc] = *(const short8*)&Qb[(size_t)qrow * DD + dc * 16 + hi * 8];
  }
  short8 onesf;
#pragma unroll
  for (int i = 0; i < 8; ++i) onesf[i] = (short)0x3F80;  // bf16 1.0

  floatx16 acc_pv[2], acc_sum;
#pragma unroll
  for (int r = 0; r < 16; ++r) { acc_pv[0][r] = 0.f; acc_pv[1][r] = 0.f; acc_sum[r] = 0.f; }

  __syncthreads();
  int cur = 0;
  for (int kv0 = 0; kv0 < SS; kv0 += 32) {
    if (kv0 + 32 < SS) {
      STAGE_KV(cur ^ 1, kv0 + 32)
      STAGE_B(cur ^ 1, (kv0 >> 5) + 1)
    }

    // C-init from blocked bias (conflict-free b64 reads)
    floatx16 c_;
#pragma unroll
    for (int g = 0; g < 4; ++g) {
      short4 b4 = *(const short4*)&Blds[cur][g * 2 + hi][q][0];
      c_[4 * g + 0] = bf2f(b4.x); c_[4 * g + 1] = bf2f(b4.y);
      c_[4 * g + 2] = bf2f(b4.z); c_[4 * g + 3] = bf2f(b4.w);
    }
    // S^T = K·Q^T + bias
    __builtin_amdgcn_s_setprio(1);
#pragma unroll
    for (int dc = 0; dc < 4; ++dc) {
      short8 kf = *(const short8*)&Klds[cur][l31][((2 * dc + hi) ^ (l31 & 7)) * 8];
      c_ = __builtin_amdgcn_mfma_f32_32x32x16_bf16(kf, qf[dc], c_, 0, 0, 0);
    }
    __builtin_amdgcn_s_setprio(0);

    // P = exp2(s) directly (no max tracking), pack to bf16
    int dd[8];
#pragma unroll
    for (int i = 0; i < 8; ++i)
      dd[i] = cvtpk(__builtin_amdgcn_exp2f(c_[2 * i]),
                    __builtin_amdgcn_exp2f(c_[2 * i + 1]));

#pragma unroll
    for (int ks2 = 0; ks2 < 2; ++ks2) {
      int a0 = dd[4 * ks2 + 0], a1 = dd[4 * ks2 + 1];
      int a2 = dd[4 * ks2 + 2], a3 = dd[4 * ks2 + 3];
      pl32swap(a0, a2);
      pl32swap(a1, a3);
      int4v w; w[0] = a0; w[1] = a1; w[2] = a2; w[3] = a3;
      short8 pf = *(short8*)&w;
      __builtin_amdgcn_s_setprio(1);
#pragma unroll
      for (int dt = 0; dt < 2; ++dt) {
        int vr = dt * 32 + l31;
        short8 vf = *(const short8*)&Vtl[cur][vr][((2 * ks2 + hi) ^ (vr & 3)) * 8];
        acc_pv[dt] = __builtin_amdgcn_mfma_f32_32x32x16_bf16(vf, pf, acc_pv[dt], 0, 0, 0);
      }
      acc_sum = __builtin_amdgcn_mfma_f32_32x32x16_bf16(onesf, pf, acc_sum, 0, 0, 0);
      __builtin_amdgcn_s_setprio(0);
    }
    __syncthreads();
    cur ^= 1;
  }
#undef STAGE_KV
#undef STAGE_B

  // epilogue: O^T (regs) -> per-wave LDS transpose (in Blds) -> coalesced store
  float inv = 1.0f / acc_sum[0];
  short* ep = (short*)Blds + wave * 2048;   // 4KB per wave, flat [32 q][64 d]
#pragma unroll
  for (int dt = 0; dt < 2; ++dt)
#pragma unroll
    for (int r = 0; r < 16; ++r) {
      int d = dt * 32 + (r & 3) + 8 * (r >> 2) + 4 * hi;
      int chunk = d >> 3, doff = d & 7;
      ep[l31 * 64 + ((chunk ^ (l31 & 7)) << 3) + doff] = f2bf(acc_pv[dt][r] * inv);
    }
  short* Ob = O + (size_t)b * SS * DD + h * DHH;
  const int rr = lane >> 3, cc = lane & 7;
#pragma unroll
  for (int ii = 0; ii < 4; ++ii) {
    int q2 = ii * 8 + rr;
    short8 vv = *(const short8*)&ep[q2 * 64 + ((cc ^ (q2 & 7)) << 3)];
    *(short8*)&Ob[(size_t)(q0 + wave * 32 + q2) * DD + cc * 8] = vv;
  }
}

// ---------------- launch ----------------
extern "C" void kernel_launch(void* const* d_in, const int* in_sizes, int n_in,
                              void* d_out, int out_size, void* d_ws, size_t ws_size,
                              hipStream_t stream) {
  const float* qa   = (const float*)d_in[0];
  const float* ma   = (const float*)d_in[1];
  const float* bias = (const float*)d_in[2];
  const float* Wq   = (const float*)d_in[3];
  const float* Wk   = (const float*)d_in[4];
  const float* Wv   = (const float*)d_in[5];
  const float* Wo   = (const float*)d_in[6];
  float* out = (float*)d_out;

  char* ws = (char*)d_ws;
  size_t off = 0;
  auto alloc = [&](size_t bytes) {
    char* p = ws + off;
    off += (bytes + 255) & ~(size_t)255;
    return p;
  };
  const size_t nQKV = (size_t)BB * SS * DD;
  short* qa_bf   = (short*)alloc(nQKV * 2);
  short* ma_bf   = (short*)alloc(nQKV * 2);
  short* bias_bk = (short*)alloc((size_t)BB * SS * SS * 2);
  short* Wqt  = (short*)alloc((size_t)DD * DD * 2);
  short* Wkvt = (short*)alloc((size_t)2 * DD * DD * 2);
  short* Wot  = (short*)alloc((size_t)DD * DD * 2);
  short* Qp   = (short*)alloc(nQKV * 2);
  short* KVp  = (short*)alloc(nQKV * 2 * 2);
  short* AOp  = (short*)alloc(nQKV * 2);
  short* VTp  = qa_bf;  // reuse: qa_bf dead after Q-projection GEMM

  const float LOG2E = 1.4426950408889634f;
  int n4a = (int)(nQKV / 4);
  cvt_kernel<<<(n4a + 255) / 256, 256, 0, stream>>>(qa, qa_bf, n4a, 1.0f);
  cvt_kernel<<<(n4a + 255) / 256, 256, 0, stream>>>(ma, ma_bf, n4a, 1.0f);

  btrans_blk<<<dim3(SS / 64, SS / 64, BB), 256, 0, stream>>>(bias, bias_bk, LOG2E);

  dim3 tg(64, 64);
  wtrans_kernel<<<tg, 256, 0, stream>>>(Wq, Wqt, 0.125f * LOG2E);
  wtrans_kernel<<<tg, 256, 0, stream>>>(Wk, Wkvt, 1.0f);
  wtrans_kernel<<<tg, 256, 0, stream>>>(Wv, Wkvt + (size_t)DD * DD, 1.0f);
  wtrans_kernel<<<tg, 256, 0, stream>>>(Wo, Wot, 1.0f);

  gemm_kernel<0><<<BB * SS / 128 * (DD / 128), 256, 0, stream>>>(qa_bf, Wqt, Qp, BB * SS, DD, DD);
  gemm_kernel<0><<<BB * SS / 128 * (2 * DD / 128), 256, 0, stream>>>(ma_bf, Wkvt, KVp, BB * SS, 2 * DD, DD);

  vtrans_kernel<<<dim3(SS / 64, DD / 64, BB), 256, 0, stream>>>(KVp + DD, VTp, 2 * DD);

  attn_kernel<<<BB * HH * (SS / 128), 256, 0, stream>>>(Qp, KVp, VTp, bias_bk, AOp, 2 * DD);

  gemm_kernel<1><<<BB * SS / 128 * (DD / 128), 256, 0, stream>>>(AOp, Wot, out, BB * SS, DD, DD);
}

// Round 11
// 296.801 us; speedup vs baseline: 1.0869x; 1.0869x over previous
//
#include <hip/hip_runtime.h>
#include <hip/hip_bf16.h>

#define BB 4
#define SS 2048
#define DD 1024
#define HH 16
#define DHH 64

typedef __attribute__((ext_vector_type(8))) short short8;
typedef __attribute__((ext_vector_type(4))) float floatx4;
typedef __attribute__((ext_vector_type(16))) float floatx16;
typedef __attribute__((ext_vector_type(4))) int int4v;

__device__ inline short f2bf(float x) {
  union { float f; unsigned u; } v; v.f = x;
  unsigned r = v.u + 0x7FFFu + ((v.u >> 16) & 1u);
  return (short)(r >> 16);
}
__device__ inline float bf2f(short x) {
  union { unsigned u; float f; } v;
  v.u = ((unsigned)(unsigned short)x) << 16;
  return v.f;
}
__device__ inline int cvtpk(float lo, float hi) {
  int r;
  asm("v_cvt_pk_bf16_f32 %0, %1, %2" : "=v"(r) : "v"(lo), "v"(hi));
  return r;
}
// DST[63:32] <-> SRC[31:0]
__device__ inline void pl32swap(int& a, int& b) {
  asm("v_permlane32_swap_b32 %0, %1" : "+v"(a), "+v"(b));
}

typedef __attribute__((address_space(1))) const unsigned int GUI;
typedef __attribute__((address_space(3))) unsigned int LUI;
__device__ inline void gload16(const void* g, void* l) {
  __builtin_amdgcn_global_load_lds((GUI*)g, (LUI*)l, 16, 0, 0);
}

// ---------------- f32 -> bf16 conversion ----------------
__global__ __launch_bounds__(256) void cvt_kernel(const float* __restrict__ in,
                                                  short* __restrict__ out, int n4,
                                                  float scale) {
  int i = blockIdx.x * 256 + threadIdx.x;
  if (i >= n4) return;
  float4 v = ((const float4*)in)[i];
  short4 o;
  o.x = f2bf(v.x * scale); o.y = f2bf(v.y * scale);
  o.z = f2bf(v.z * scale); o.w = f2bf(v.w * scale);
  ((short4*)out)[i] = o;
}

// ---------------- weight transpose + convert (+scale) ----------------
__global__ __launch_bounds__(256) void wtrans_kernel(const float* __restrict__ in,
                                                     short* __restrict__ out, float scale) {
  __shared__ float tile[16][17];
  int tx = threadIdx.x & 15, ty = threadIdx.x >> 4;
  int k = blockIdx.y * 16 + ty;
  int n = blockIdx.x * 16 + tx;
  tile[ty][tx] = in[(size_t)k * 1024 + n];
  __syncthreads();
  int n2 = blockIdx.x * 16 + ty;
  int k2 = blockIdx.y * 16 + tx;
  out[(size_t)n2 * 1024 + k2] = f2bf(tile[tx][ty] * scale);
}

// ---------------- bias -> blocked bf16 layout (64-kv tiles, r7 form) ----------
// out[((b*32+kvtile)*16 + s)*8192 + q*4 + j] = bias[b][q][kvtile*64 + kvt*32+8g+4hi+j]
// where s = kvt*8 + g*2 + hi.
__global__ __launch_bounds__(256) void btrans_blk(const float* __restrict__ in,
                                                  short* __restrict__ out, float scale) {
  __shared__ short tile[64][68];
  const int t = threadIdx.x;
  const int b = blockIdx.z;
  const int q0 = blockIdx.x * 64, kv0 = blockIdx.y * 64;
  const float* gin = in + ((size_t)b * SS + q0) * SS + kv0;
#pragma unroll
  for (int i = 0; i < 4; ++i) {
    int idx = t + 256 * i;
    int row = idx >> 4, c4 = idx & 15;
    float4 v = ((const float4*)(gin + (size_t)row * SS))[c4];
    tile[row][c4 * 4 + 0] = f2bf(v.x * scale);
    tile[row][c4 * 4 + 1] = f2bf(v.y * scale);
    tile[row][c4 * 4 + 2] = f2bf(v.z * scale);
    tile[row][c4 * 4 + 3] = f2bf(v.w * scale);
  }
  __syncthreads();
  short* gout = out + (size_t)((b * 32 + (kv0 >> 6)) * 16) * 8192 + (size_t)q0 * 4;
#pragma unroll
  for (int i = 0; i < 4; ++i) {
    int idx = t + 256 * i;
    int s = idx >> 6, ql = idx & 63;
    int kvt = s >> 3, g = (s >> 1) & 3, hi = s & 1;
    short4 v = *(const short4*)&tile[ql][kvt * 32 + g * 8 + hi * 4];
    *(short4*)&gout[(size_t)s * 8192 + (size_t)ql * 4] = v;
  }
}

// ---------------- V transpose: [B][S][ldin] cols 0..1023 -> [B][1024][S] --------
__global__ __launch_bounds__(256) void vtrans_kernel(const short* __restrict__ in,
                                                     short* __restrict__ out, int ldin) {
  __shared__ int tile[64][33];
  const int t = threadIdx.x;
  const int b = blockIdx.z;
  const int s0 = blockIdx.x * 64, d0 = blockIdx.y * 64;
  const int* gin = (const int*)(in + (size_t)b * SS * ldin);
  const int ldi2 = ldin >> 1;
  int* gout = (int*)(out + (size_t)b * DD * SS);
#pragma unroll
  for (int i = 0; i < 8; ++i) {
    int idx = t + i * 256;
    int row = idx >> 5, col = idx & 31;
    tile[row][col] = gin[(size_t)(s0 + row) * ldi2 + (d0 >> 1) + col];
  }
  __syncthreads();
#pragma unroll
  for (int i = 0; i < 8; ++i) {
    int idx = t + i * 256;
    int d = idx >> 5, spc = idx & 31;
    int a = tile[2 * spc][d >> 1];
    int c = tile[2 * spc + 1][d >> 1];
    int o = (d & 1) ? (((a >> 16) & 0xffff) | (c & 0xffff0000))
                    : ((a & 0xffff) | (c << 16));
    gout[(size_t)(d0 + d) * (SS / 2) + (s0 >> 1) + spc] = o;
  }
}

// ---------------- bf16 MFMA GEMM, dbuf 2-phase, XCD-swizzled, T2 LDS swizzle ----
template<int OUT_F32>
__global__ __launch_bounds__(256) void gemm_kernel(const short* __restrict__ A,
                                                   const short* __restrict__ Bt,
                                                   void* __restrict__ Cout,
                                                   int M, int N, int K) {
  __shared__ alignas(16) short As[2][128][32];
  __shared__ alignas(16) short Bs[2][128][32];
  const int t = threadIdx.x;
  const int lane = t & 63, wave = t >> 6;
  const int wr = wave >> 1, wc = wave & 1;
  const int l15 = lane & 15, l4 = lane >> 4;

  const int hw = blockIdx.x;
  const int L = (hw & 7) * ((int)gridDim.x >> 3) + (hw >> 3);
  const int NY = N >> 7;
  const int bxm = L / NY, byn = L % NY;

  floatx4 acc[4][4];
#pragma unroll
  for (int i = 0; i < 4; ++i)
#pragma unroll
    for (int j = 0; j < 4; ++j) acc[i][j] = (floatx4){0.f, 0.f, 0.f, 0.f};

  const short* Ag = A + (size_t)bxm * 128 * K;
  const short* Bg = Bt + (size_t)byn * 128 * K;
  const int o0 = t * 16, o1 = t * 16 + 4096;
  const int r0 = o0 >> 6, r1 = o1 >> 6;
  const int c0 = (((o0 >> 1) & 31) ^ ((r0 & 3) << 3));
  const int c1 = (((o1 >> 1) & 31) ^ ((r1 & 3) << 3));
  const int rbase = wr * 64 + l15;
  const int cbase = wc * 64 + l15;
  const int koff = (l4 ^ (l15 & 3)) * 8;

#define GSTAGE(buf, k0)                                                  \
  gload16(&Ag[(size_t)r0 * K + (k0) + c0], (char*)As[buf] + o0);         \
  gload16(&Bg[(size_t)r0 * K + (k0) + c0], (char*)Bs[buf] + o0);         \
  gload16(&Ag[(size_t)r1 * K + (k0) + c1], (char*)As[buf] + o1);         \
  gload16(&Bg[(size_t)r1 * K + (k0) + c1], (char*)Bs[buf] + o1);

  GSTAGE(0, 0)
  __syncthreads();
  int cur = 0;
  for (int k0 = 0; k0 < K; k0 += 32) {
    if (k0 + 32 < K) { GSTAGE(cur ^ 1, k0 + 32) }
    short8 af[4], bfr[4];
#pragma unroll
    for (int mi = 0; mi < 4; ++mi) af[mi] = *(const short8*)&As[cur][rbase + mi * 16][koff];
#pragma unroll
    for (int ni = 0; ni < 4; ++ni) bfr[ni] = *(const short8*)&Bs[cur][cbase + ni * 16][koff];
    __builtin_amdgcn_s_setprio(1);
#pragma unroll
    for (int mi = 0; mi < 4; ++mi)
#pragma unroll
      for (int ni = 0; ni < 4; ++ni)
        acc[mi][ni] = __builtin_amdgcn_mfma_f32_16x16x32_bf16(af[mi], bfr[ni], acc[mi][ni], 0, 0, 0);
    __builtin_amdgcn_s_setprio(0);
    __syncthreads();
    cur ^= 1;
  }
#undef GSTAGE

  const int row0 = bxm * 128 + wr * 64 + l4 * 4;
  const int col0 = byn * 128 + wc * 64 + l15;
  if (OUT_F32) {
    float* Cf = (float*)Cout;
#pragma unroll
    for (int mi = 0; mi < 4; ++mi)
#pragma unroll
      for (int ni = 0; ni < 4; ++ni)
#pragma unroll
        for (int r = 0; r < 4; ++r)
          Cf[(size_t)(row0 + mi * 16 + r) * N + col0 + ni * 16] = acc[mi][ni][r];
  } else {
    short* Cs = (short*)Cout;
#pragma unroll
    for (int mi = 0; mi < 4; ++mi)
#pragma unroll
      for (int ni = 0; ni < 4; ++ni)
#pragma unroll
        for (int r = 0; r < 4; ++r)
          Cs[(size_t)(row0 + mi * 16 + r) * N + col0 + ni * 16] = f2bf(acc[mi][ni][r]);
  }
}

// ---------------- flash attention: no-max log2 softmax, bias in regs -----------
// r9 structure (KVBLK=64, 1 barrier/iter, K/V DMA dbuf) with Blds removed:
// bias prefetched per-lane from blocked global layout (8 coalesced b64/iter).
// LDS = 32KB -> 4 blocks/CU (grid cap). 1-D grid 1024, XCD-chunked.
__global__ __launch_bounds__(256) void attn_kernel(const short* __restrict__ Q,
                                                   const short* __restrict__ K,
                                                   const short* __restrict__ VT,
                                                   const short* __restrict__ bias_blk,
                                                   short* __restrict__ O, int ldk) {
  __shared__ alignas(16) short Klds[2][64][64];      // 16KB
  __shared__ alignas(16) short Vtl[2][64][64];       // 16KB

  const int t = threadIdx.x;
  const int lane = t & 63, wave = t >> 6;
  const int hw = blockIdx.x;
  const int L = (hw & 7) * 128 + (hw >> 3);
  const int bh = L >> 4;
  const int q0 = (L & 15) * 128;
  const int b = bh >> 4, h = bh & 15;
  const int l31 = lane & 31, hi = lane >> 5;

  const short* Qb = Q + (size_t)b * SS * DD + h * DHH;
  const short* Kb = K + (size_t)b * SS * ldk + h * DHH;
  const short* VTb = VT + ((size_t)b * DD + h * DHH) * SS;
  // per-lane bias base: slice = (b*32+kvtile)*16 + kvt*8 + g*2 + hi; off = q*4
  const short* Bl = bias_blk + (size_t)(b * 32 * 16) * 8192 + (size_t)hi * 8192
                    + (size_t)(q0 + wave * 32 + l31) * 4;

  const int sr0 = t >> 3;
  const int scb = ((t & 7) ^ (sr0 & 7)) * 8;

#define STAGE_KV(buf, kvb)                                                              \
  {                                                                                     \
    gload16(&Kb[(size_t)((kvb) + sr0) * ldk + scb], (char*)&Klds[buf][0][0] + t * 16);  \
    gload16(&Kb[(size_t)((kvb) + sr0 + 32) * ldk + scb],                                \
            (char*)&Klds[buf][0][0] + 4096 + t * 16);                                   \
    gload16(&VTb[(size_t)sr0 * SS + (kvb) + scb], (char*)&Vtl[buf][0][0] + t * 16);     \
    gload16(&VTb[(size_t)(sr0 + 32) * SS + (kvb) + scb],                                \
            (char*)&Vtl[buf][0][0] + 4096 + t * 16);                                    \
  }
#define BIAS_PREF(kvb)                                                                  \
  {                                                                                     \
    int kt16 = ((kvb) >> 6) << 4;                                                       \
    _Pragma("unroll")                                                                   \
    for (int kvt = 0; kvt < 2; ++kvt)                                                   \
      _Pragma("unroll")                                                                 \
      for (int g = 0; g < 4; ++g)                                                       \
        br[kvt * 4 + g] = *(const short4*)&Bl[(size_t)(kt16 + kvt * 8 + g * 2) * 8192]; \
  }

  short4 br[8];
  STAGE_KV(0, 0)
  BIAS_PREF(0)

  const int q = wave * 32 + l31;
  short8 qf[4];
  {
    int qrow = q0 + q;
#pragma unroll
    for (int dc = 0; dc < 4; ++dc)
      qf[dc] = *(const short8*)&Qb[(size_t)qrow * DD + dc * 16 + hi * 8];
  }
  short8 onesf;
#pragma unroll
  for (int i = 0; i < 8; ++i) onesf[i] = (short)0x3F80;  // bf16 1.0

  floatx16 acc_pv[2], acc_sum;
#pragma unroll
  for (int r = 0; r < 16; ++r) { acc_pv[0][r] = 0.f; acc_pv[1][r] = 0.f; acc_sum[r] = 0.f; }

  __syncthreads();
  int cur = 0;
  for (int kv0 = 0; kv0 < SS; kv0 += 64) {
    if (kv0 + 64 < SS) STAGE_KV(cur ^ 1, kv0 + 64)

#pragma unroll
    for (int kvt = 0; kvt < 2; ++kvt) {
      // C-init from prefetched bias regs
      floatx16 c_;
#pragma unroll
      for (int g = 0; g < 4; ++g) {
        short4 b4 = br[kvt * 4 + g];
        c_[4 * g + 0] = bf2f(b4.x); c_[4 * g + 1] = bf2f(b4.y);
        c_[4 * g + 2] = bf2f(b4.z); c_[4 * g + 3] = bf2f(b4.w);
      }
      int kr = kvt * 32 + l31;
      __builtin_amdgcn_s_setprio(1);
#pragma unroll
      for (int dc = 0; dc < 4; ++dc) {
        short8 kf = *(const short8*)&Klds[cur][kr][((2 * dc + hi) ^ (kr & 7)) * 8];
        c_ = __builtin_amdgcn_mfma_f32_32x32x16_bf16(kf, qf[dc], c_, 0, 0, 0);
      }
      __builtin_amdgcn_s_setprio(0);

      // refill bias regs for next tile right after last consumption
      if (kvt == 1 && kv0 + 64 < SS) BIAS_PREF(kv0 + 64)

      // P = exp2(s) directly (no max tracking), pack to bf16
      int dd[8];
#pragma unroll
      for (int i = 0; i < 8; ++i)
        dd[i] = cvtpk(__builtin_amdgcn_exp2f(c_[2 * i]),
                      __builtin_amdgcn_exp2f(c_[2 * i + 1]));

#pragma unroll
      for (int ks2 = 0; ks2 < 2; ++ks2) {
        int a0 = dd[4 * ks2 + 0], a1 = dd[4 * ks2 + 1];
        int a2 = dd[4 * ks2 + 2], a3 = dd[4 * ks2 + 3];
        pl32swap(a0, a2);
        pl32swap(a1, a3);
        int4v w; w[0] = a0; w[1] = a1; w[2] = a2; w[3] = a3;
        short8 pf = *(short8*)&w;
        int ks = kvt * 2 + ks2;
        __builtin_amdgcn_s_setprio(1);
#pragma unroll
        for (int dt = 0; dt < 2; ++dt) {
          int vr = dt * 32 + l31;
          short8 vf = *(const short8*)&Vtl[cur][vr][((2 * ks + hi) ^ (vr & 7)) * 8];
          acc_pv[dt] = __builtin_amdgcn_mfma_f32_32x32x16_bf16(vf, pf, acc_pv[dt], 0, 0, 0);
        }
        acc_sum = __builtin_amdgcn_mfma_f32_32x32x16_bf16(onesf, pf, acc_sum, 0, 0, 0);
        __builtin_amdgcn_s_setprio(0);
      }
    }
    __syncthreads();
    cur ^= 1;
  }
#undef STAGE_KV
#undef BIAS_PREF

  // epilogue: O^T (regs) -> per-wave LDS transpose -> coalesced store
  float inv = 1.0f / acc_sum[0];
  short* ep = (short*)Klds + wave * 2048;   // 4KB per wave, flat [32 q][64 d]
#pragma unroll
  for (int dt = 0; dt < 2; ++dt)
#pragma unroll
    for (int r = 0; r < 16; ++r) {
      int d = dt * 32 + (r & 3) + 8 * (r >> 2) + 4 * hi;
      int chunk = d >> 3, doff = d & 7;
      ep[l31 * 64 + ((chunk ^ (l31 & 7)) << 3) + doff] = f2bf(acc_pv[dt][r] * inv);
    }
  short* Ob = O + (size_t)b * SS * DD + h * DHH;
  const int rr = lane >> 3, cc = lane & 7;
#pragma unroll
  for (int ii = 0; ii < 4; ++ii) {
    int q2 = ii * 8 + rr;
    short8 vv = *(const short8*)&ep[q2 * 64 + ((cc ^ (q2 & 7)) << 3)];
    *(short8*)&Ob[(size_t)(q0 + wave * 32 + q2) * DD + cc * 8] = vv;
  }
}

// ---------------- launch ----------------
extern "C" void kernel_launch(void* const* d_in, const int* in_sizes, int n_in,
                              void* d_out, int out_size, void* d_ws, size_t ws_size,
                              hipStream_t stream) {
  const float* qa   = (const float*)d_in[0];
  const float* ma   = (const float*)d_in[1];
  const float* bias = (const float*)d_in[2];
  const float* Wq   = (const float*)d_in[3];
  const float* Wk   = (const float*)d_in[4];
  const float* Wv   = (const float*)d_in[5];
  const float* Wo   = (const float*)d_in[6];
  float* out = (float*)d_out;

  char* ws = (char*)d_ws;
  size_t off = 0;
  auto alloc = [&](size_t bytes) {
    char* p = ws + off;
    off += (bytes + 255) & ~(size_t)255;
    return p;
  };
  const size_t nQKV = (size_t)BB * SS * DD;
  short* qa_bf   = (short*)alloc(nQKV * 2);
  short* ma_bf   = (short*)alloc(nQKV * 2);
  short* bias_bk = (short*)alloc((size_t)BB * SS * SS * 2);
  short* Wqt  = (short*)alloc((size_t)DD * DD * 2);
  short* Wkvt = (short*)alloc((size_t)2 * DD * DD * 2);
  short* Wot  = (short*)alloc((size_t)DD * DD * 2);
  short* Qp   = (short*)alloc(nQKV * 2);
  short* KVp  = (short*)alloc(nQKV * 2 * 2);
  short* AOp  = (short*)alloc(nQKV * 2);
  short* VTp  = qa_bf;  // reuse: qa_bf dead after Q-projection GEMM

  const float LOG2E = 1.4426950408889634f;
  int n4a = (int)(nQKV / 4);
  cvt_kernel<<<(n4a + 255) / 256, 256, 0, stream>>>(qa, qa_bf, n4a, 1.0f);
  cvt_kernel<<<(n4a + 255) / 256, 256, 0, stream>>>(ma, ma_bf, n4a, 1.0f);

  btrans_blk<<<dim3(SS / 64, SS / 64, BB), 256, 0, stream>>>(bias, bias_bk, LOG2E);

  dim3 tg(64, 64);
  wtrans_kernel<<<tg, 256, 0, stream>>>(Wq, Wqt, 0.125f * LOG2E);
  wtrans_kernel<<<tg, 256, 0, stream>>>(Wk, Wkvt, 1.0f);
  wtrans_kernel<<<tg, 256, 0, stream>>>(Wv, Wkvt + (size_t)DD * DD, 1.0f);
  wtrans_kernel<<<tg, 256, 0, stream>>>(Wo, Wot, 1.0f);

  gemm_kernel<0><<<BB * SS / 128 * (DD / 128), 256, 0, stream>>>(qa_bf, Wqt, Qp, BB * SS, DD, DD);
  gemm_kernel<0><<<BB * SS / 128 * (2 * DD / 128), 256, 0, stream>>>(ma_bf, Wkvt, KVp, BB * SS, 2 * DD, DD);

  vtrans_kernel<<<dim3(SS / 64, DD / 64, BB), 256, 0, stream>>>(KVp + DD, VTp, 2 * DD);

  attn_kernel<<<BB * HH * (SS / 128), 256, 0, stream>>>(Qp, KVp, VTp, bias_bk, AOp, 2 * DD);

  gemm_kernel<1><<<BB * SS / 128 * (DD / 128), 256, 0, stream>>>(AOp, Wot, out, BB * SS, DD, DD);
}

// Round 12
// 279.605 us; speedup vs baseline: 1.1537x; 1.0615x over previous
//
#include <hip/hip_runtime.h>
#include <hip/hip_bf16.h>

#define BB 4
#define SS 2048
#define DD 1024
#define HH 16
#define DHH 64

typedef __attribute__((ext_vector_type(8))) short short8;
typedef __attribute__((ext_vector_type(4))) float floatx4;
typedef __attribute__((ext_vector_type(16))) float floatx16;
typedef __attribute__((ext_vector_type(4))) int int4v;

__device__ inline short f2bf(float x) {
  union { float f; unsigned u; } v; v.f = x;
  unsigned r = v.u + 0x7FFFu + ((v.u >> 16) & 1u);
  return (short)(r >> 16);
}
__device__ inline float bf2f(short x) {
  union { unsigned u; float f; } v;
  v.u = ((unsigned)(unsigned short)x) << 16;
  return v.f;
}
__device__ inline int cvtpk(float lo, float hi) {
  int r;
  asm("v_cvt_pk_bf16_f32 %0, %1, %2" : "=v"(r) : "v"(lo), "v"(hi));
  return r;
}
// DST[63:32] <-> SRC[31:0]
__device__ inline void pl32swap(int& a, int& b) {
  asm("v_permlane32_swap_b32 %0, %1" : "+v"(a), "+v"(b));
}

typedef __attribute__((address_space(1))) const unsigned int GUI;
typedef __attribute__((address_space(3))) unsigned int LUI;
__device__ inline void gload16(const void* g, void* l) {
  __builtin_amdgcn_global_load_lds((GUI*)g, (LUI*)l, 16, 0, 0);
}

// ---------------- f32 -> bf16 conversion ----------------
__global__ __launch_bounds__(256) void cvt_kernel(const float* __restrict__ in,
                                                  short* __restrict__ out, int n4,
                                                  float scale) {
  int i = blockIdx.x * 256 + threadIdx.x;
  if (i >= n4) return;
  float4 v = ((const float4*)in)[i];
  short4 o;
  o.x = f2bf(v.x * scale); o.y = f2bf(v.y * scale);
  o.z = f2bf(v.z * scale); o.w = f2bf(v.w * scale);
  ((short4*)out)[i] = o;
}

// ---------------- weight transpose + convert (+scale) ----------------
__global__ __launch_bounds__(256) void wtrans_kernel(const float* __restrict__ in,
                                                     short* __restrict__ out, float scale) {
  __shared__ float tile[16][17];
  int tx = threadIdx.x & 15, ty = threadIdx.x >> 4;
  int k = blockIdx.y * 16 + ty;
  int n = blockIdx.x * 16 + tx;
  tile[ty][tx] = in[(size_t)k * 1024 + n];
  __syncthreads();
  int n2 = blockIdx.x * 16 + ty;
  int k2 = blockIdx.y * 16 + tx;
  out[(size_t)n2 * 1024 + k2] = f2bf(tile[tx][ty] * scale);
}

// ---------------- bias -> blocked bf16 layout (64-kv tiles) -------------------
// out[((b*32+kvtile)*16 + s)*8192 + q*4 + j] = bias[b][q][kvtile*64 + kvt*32+8g+4hi+j]
// where s = kvt*8 + g*2 + hi.
__global__ __launch_bounds__(256) void btrans_blk(const float* __restrict__ in,
                                                  short* __restrict__ out, float scale) {
  __shared__ short tile[64][68];
  const int t = threadIdx.x;
  const int b = blockIdx.z;
  const int q0 = blockIdx.x * 64, kv0 = blockIdx.y * 64;
  const float* gin = in + ((size_t)b * SS + q0) * SS + kv0;
#pragma unroll
  for (int i = 0; i < 4; ++i) {
    int idx = t + 256 * i;
    int row = idx >> 4, c4 = idx & 15;
    float4 v = ((const float4*)(gin + (size_t)row * SS))[c4];
    tile[row][c4 * 4 + 0] = f2bf(v.x * scale);
    tile[row][c4 * 4 + 1] = f2bf(v.y * scale);
    tile[row][c4 * 4 + 2] = f2bf(v.z * scale);
    tile[row][c4 * 4 + 3] = f2bf(v.w * scale);
  }
  __syncthreads();
  short* gout = out + (size_t)((b * 32 + (kv0 >> 6)) * 16) * 8192 + (size_t)q0 * 4;
#pragma unroll
  for (int i = 0; i < 4; ++i) {
    int idx = t + 256 * i;
    int s = idx >> 6, ql = idx & 63;
    int kvt = s >> 3, g = (s >> 1) & 3, hi = s & 1;
    short4 v = *(const short4*)&tile[ql][kvt * 32 + g * 8 + hi * 4];
    *(short4*)&gout[(size_t)s * 8192 + (size_t)ql * 4] = v;
  }
}

// ---------------- V transpose: [B][S][ldin] cols 0..1023 -> [B][1024][S] --------
__global__ __launch_bounds__(256) void vtrans_kernel(const short* __restrict__ in,
                                                     short* __restrict__ out, int ldin) {
  __shared__ int tile[64][33];
  const int t = threadIdx.x;
  const int b = blockIdx.z;
  const int s0 = blockIdx.x * 64, d0 = blockIdx.y * 64;
  const int* gin = (const int*)(in + (size_t)b * SS * ldin);
  const int ldi2 = ldin >> 1;
  int* gout = (int*)(out + (size_t)b * DD * SS);
#pragma unroll
  for (int i = 0; i < 8; ++i) {
    int idx = t + i * 256;
    int row = idx >> 5, col = idx & 31;
    tile[row][col] = gin[(size_t)(s0 + row) * ldi2 + (d0 >> 1) + col];
  }
  __syncthreads();
#pragma unroll
  for (int i = 0; i < 8; ++i) {
    int idx = t + i * 256;
    int d = idx >> 5, spc = idx & 31;
    int a = tile[2 * spc][d >> 1];
    int c = tile[2 * spc + 1][d >> 1];
    int o = (d & 1) ? (((a >> 16) & 0xffff) | (c & 0xffff0000))
                    : ((a & 0xffff) | (c << 16));
    gout[(size_t)(d0 + d) * (SS / 2) + (s0 >> 1) + spc] = o;
  }
}

// ---------------- bf16 MFMA GEMM, dbuf 2-phase, XCD-swizzled, T2 LDS swizzle ----
template<int OUT_F32>
__global__ __launch_bounds__(256) void gemm_kernel(const short* __restrict__ A,
                                                   const short* __restrict__ Bt,
                                                   void* __restrict__ Cout,
                                                   int M, int N, int K) {
  __shared__ alignas(16) short As[2][128][32];
  __shared__ alignas(16) short Bs[2][128][32];
  const int t = threadIdx.x;
  const int lane = t & 63, wave = t >> 6;
  const int wr = wave >> 1, wc = wave & 1;
  const int l15 = lane & 15, l4 = lane >> 4;

  const int hw = blockIdx.x;
  const int L = (hw & 7) * ((int)gridDim.x >> 3) + (hw >> 3);
  const int NY = N >> 7;
  const int bxm = L / NY, byn = L % NY;

  floatx4 acc[4][4];
#pragma unroll
  for (int i = 0; i < 4; ++i)
#pragma unroll
    for (int j = 0; j < 4; ++j) acc[i][j] = (floatx4){0.f, 0.f, 0.f, 0.f};

  const short* Ag = A + (size_t)bxm * 128 * K;
  const short* Bg = Bt + (size_t)byn * 128 * K;
  const int o0 = t * 16, o1 = t * 16 + 4096;
  const int r0 = o0 >> 6, r1 = o1 >> 6;
  const int c0 = (((o0 >> 1) & 31) ^ ((r0 & 3) << 3));
  const int c1 = (((o1 >> 1) & 31) ^ ((r1 & 3) << 3));
  const int rbase = wr * 64 + l15;
  const int cbase = wc * 64 + l15;
  const int koff = (l4 ^ (l15 & 3)) * 8;

#define GSTAGE(buf, k0)                                                  \
  gload16(&Ag[(size_t)r0 * K + (k0) + c0], (char*)As[buf] + o0);         \
  gload16(&Bg[(size_t)r0 * K + (k0) + c0], (char*)Bs[buf] + o0);         \
  gload16(&Ag[(size_t)r1 * K + (k0) + c1], (char*)As[buf] + o1);         \
  gload16(&Bg[(size_t)r1 * K + (k0) + c1], (char*)Bs[buf] + o1);

  GSTAGE(0, 0)
  __syncthreads();
  int cur = 0;
  for (int k0 = 0; k0 < K; k0 += 32) {
    if (k0 + 32 < K) { GSTAGE(cur ^ 1, k0 + 32) }
    short8 af[4], bfr[4];
#pragma unroll
    for (int mi = 0; mi < 4; ++mi) af[mi] = *(const short8*)&As[cur][rbase + mi * 16][koff];
#pragma unroll
    for (int ni = 0; ni < 4; ++ni) bfr[ni] = *(const short8*)&Bs[cur][cbase + ni * 16][koff];
    __builtin_amdgcn_s_setprio(1);
#pragma unroll
    for (int mi = 0; mi < 4; ++mi)
#pragma unroll
      for (int ni = 0; ni < 4; ++ni)
        acc[mi][ni] = __builtin_amdgcn_mfma_f32_16x16x32_bf16(af[mi], bfr[ni], acc[mi][ni], 0, 0, 0);
    __builtin_amdgcn_s_setprio(0);
    __syncthreads();
    cur ^= 1;
  }
#undef GSTAGE

  const int row0 = bxm * 128 + wr * 64 + l4 * 4;
  const int col0 = byn * 128 + wc * 64 + l15;
  if (OUT_F32) {
    float* Cf = (float*)Cout;
#pragma unroll
    for (int mi = 0; mi < 4; ++mi)
#pragma unroll
      for (int ni = 0; ni < 4; ++ni)
#pragma unroll
        for (int r = 0; r < 4; ++r)
          Cf[(size_t)(row0 + mi * 16 + r) * N + col0 + ni * 16] = acc[mi][ni][r];
  } else {
    short* Cs = (short*)Cout;
#pragma unroll
    for (int mi = 0; mi < 4; ++mi)
#pragma unroll
      for (int ni = 0; ni < 4; ++ni)
#pragma unroll
        for (int r = 0; r < 4; ++r)
          Cs[(size_t)(row0 + mi * 16 + r) * N + col0 + ni * 16] = f2bf(acc[mi][ni][r]);
  }
}

// ---------------- flash attention: no-max log2 softmax, VALU row-sum -----------
// r11 structure; acc_sum MFMA replaced by per-lane f32 partial sum (the lane's
// 32 S-entries are exactly its q-column's kv rows) -> frees 16 AGPR + 4 VGPR,
// total regs < 128 -> 4 waves/SIMD. launch_bounds(256,4) pins the allocator.
__global__ __launch_bounds__(256, 4) void attn_kernel(const short* __restrict__ Q,
                                                      const short* __restrict__ K,
                                                      const short* __restrict__ VT,
                                                      const short* __restrict__ bias_blk,
                                                      short* __restrict__ O, int ldk) {
  __shared__ alignas(16) short Klds[2][64][64];      // 16KB
  __shared__ alignas(16) short Vtl[2][64][64];       // 16KB

  const int t = threadIdx.x;
  const int lane = t & 63, wave = t >> 6;
  const int hw = blockIdx.x;
  const int L = (hw & 7) * 128 + (hw >> 3);
  const int bh = L >> 4;
  const int q0 = (L & 15) * 128;
  const int b = bh >> 4, h = bh & 15;
  const int l31 = lane & 31, hi = lane >> 5;

  const short* Qb = Q + (size_t)b * SS * DD + h * DHH;
  const short* Kb = K + (size_t)b * SS * ldk + h * DHH;
  const short* VTb = VT + ((size_t)b * DD + h * DHH) * SS;
  const short* Bl = bias_blk + (size_t)(b * 32 * 16) * 8192 + (size_t)hi * 8192
                    + (size_t)(q0 + wave * 32 + l31) * 4;

  const int sr0 = t >> 3;
  const int scb = ((t & 7) ^ (sr0 & 7)) * 8;

#define STAGE_KV(buf, kvb)                                                              \
  {                                                                                     \
    gload16(&Kb[(size_t)((kvb) + sr0) * ldk + scb], (char*)&Klds[buf][0][0] + t * 16);  \
    gload16(&Kb[(size_t)((kvb) + sr0 + 32) * ldk + scb],                                \
            (char*)&Klds[buf][0][0] + 4096 + t * 16);                                   \
    gload16(&VTb[(size_t)sr0 * SS + (kvb) + scb], (char*)&Vtl[buf][0][0] + t * 16);     \
    gload16(&VTb[(size_t)(sr0 + 32) * SS + (kvb) + scb],                                \
            (char*)&Vtl[buf][0][0] + 4096 + t * 16);                                    \
  }
#define BIAS_PREF(kvb)                                                                  \
  {                                                                                     \
    int kt16 = ((kvb) >> 6) << 4;                                                       \
    _Pragma("unroll")                                                                   \
    for (int kvt = 0; kvt < 2; ++kvt)                                                   \
      _Pragma("unroll")                                                                 \
      for (int g = 0; g < 4; ++g)                                                       \
        br[kvt * 4 + g] = *(const short4*)&Bl[(size_t)(kt16 + kvt * 8 + g * 2) * 8192]; \
  }

  short4 br[8];
  STAGE_KV(0, 0)
  BIAS_PREF(0)

  const int q = wave * 32 + l31;
  short8 qf[4];
  {
    int qrow = q0 + q;
#pragma unroll
    for (int dc = 0; dc < 4; ++dc)
      qf[dc] = *(const short8*)&Qb[(size_t)qrow * DD + dc * 16 + hi * 8];
  }

  floatx16 acc_pv[2];
#pragma unroll
  for (int r = 0; r < 16; ++r) { acc_pv[0][r] = 0.f; acc_pv[1][r] = 0.f; }
  float psum = 0.f;   // per-lane partial denominator (this lane's 16 kv rows/kvt)

  __syncthreads();
  int cur = 0;
  for (int kv0 = 0; kv0 < SS; kv0 += 64) {
    if (kv0 + 64 < SS) STAGE_KV(cur ^ 1, kv0 + 64)

#pragma unroll
    for (int kvt = 0; kvt < 2; ++kvt) {
      // C-init from prefetched bias regs
      floatx16 c_;
#pragma unroll
      for (int g = 0; g < 4; ++g) {
        short4 b4 = br[kvt * 4 + g];
        c_[4 * g + 0] = bf2f(b4.x); c_[4 * g + 1] = bf2f(b4.y);
        c_[4 * g + 2] = bf2f(b4.z); c_[4 * g + 3] = bf2f(b4.w);
      }
      int kr = kvt * 32 + l31;
      __builtin_amdgcn_s_setprio(1);
#pragma unroll
      for (int dc = 0; dc < 4; ++dc) {
        short8 kf = *(const short8*)&Klds[cur][kr][((2 * dc + hi) ^ (kr & 7)) * 8];
        c_ = __builtin_amdgcn_mfma_f32_32x32x16_bf16(kf, qf[dc], c_, 0, 0, 0);
      }
      __builtin_amdgcn_s_setprio(0);

      if (kvt == 1 && kv0 + 64 < SS) BIAS_PREF(kv0 + 64)

      // P = exp2(s) directly; accumulate per-lane sum; pack to bf16
      int dd[8];
#pragma unroll
      for (int i = 0; i < 8; ++i) {
        float e0 = __builtin_amdgcn_exp2f(c_[2 * i]);
        float e1 = __builtin_amdgcn_exp2f(c_[2 * i + 1]);
        psum += e0 + e1;
        dd[i] = cvtpk(e0, e1);
      }

#pragma unroll
      for (int ks2 = 0; ks2 < 2; ++ks2) {
        int a0 = dd[4 * ks2 + 0], a1 = dd[4 * ks2 + 1];
        int a2 = dd[4 * ks2 + 2], a3 = dd[4 * ks2 + 3];
        pl32swap(a0, a2);
        pl32swap(a1, a3);
        int4v w; w[0] = a0; w[1] = a1; w[2] = a2; w[3] = a3;
        short8 pf = *(short8*)&w;
        int ks = kvt * 2 + ks2;
        __builtin_amdgcn_s_setprio(1);
#pragma unroll
        for (int dt = 0; dt < 2; ++dt) {
          int vr = dt * 32 + l31;
          short8 vf = *(const short8*)&Vtl[cur][vr][((2 * ks + hi) ^ (vr & 7)) * 8];
          acc_pv[dt] = __builtin_amdgcn_mfma_f32_32x32x16_bf16(vf, pf, acc_pv[dt], 0, 0, 0);
        }
        __builtin_amdgcn_s_setprio(0);
      }
    }
    __syncthreads();
    cur ^= 1;
  }
#undef STAGE_KV
#undef BIAS_PREF

  // denominator: own half + partner half (lane +/- 32 holds the other 16 kv rows)
  float ssum = psum + __shfl_xor(psum, 32);
  float inv = 1.0f / ssum;

  // epilogue: O^T (regs) -> per-wave LDS transpose -> coalesced store
  short* ep = (short*)Klds + wave * 2048;   // 4KB per wave, flat [32 q][64 d]
#pragma unroll
  for (int dt = 0; dt < 2; ++dt)
#pragma unroll
    for (int r = 0; r < 16; ++r) {
      int d = dt * 32 + (r & 3) + 8 * (r >> 2) + 4 * hi;
      int chunk = d >> 3, doff = d & 7;
      ep[l31 * 64 + ((chunk ^ (l31 & 7)) << 3) + doff] = f2bf(acc_pv[dt][r] * inv);
    }
  short* Ob = O + (size_t)b * SS * DD + h * DHH;
  const int rr = lane >> 3, cc = lane & 7;
#pragma unroll
  for (int ii = 0; ii < 4; ++ii) {
    int q2 = ii * 8 + rr;
    short8 vv = *(const short8*)&ep[q2 * 64 + ((cc ^ (q2 & 7)) << 3)];
    *(short8*)&Ob[(size_t)(q0 + wave * 32 + q2) * DD + cc * 8] = vv;
  }
}

// ---------------- launch ----------------
extern "C" void kernel_launch(void* const* d_in, const int* in_sizes, int n_in,
                              void* d_out, int out_size, void* d_ws, size_t ws_size,
                              hipStream_t stream) {
  const float* qa   = (const float*)d_in[0];
  const float* ma   = (const float*)d_in[1];
  const float* bias = (const float*)d_in[2];
  const float* Wq   = (const float*)d_in[3];
  const float* Wk   = (const float*)d_in[4];
  const float* Wv   = (const float*)d_in[5];
  const float* Wo   = (const float*)d_in[6];
  float* out = (float*)d_out;

  char* ws = (char*)d_ws;
  size_t off = 0;
  auto alloc = [&](size_t bytes) {
    char* p = ws + off;
    off += (bytes + 255) & ~(size_t)255;
    return p;
  };
  const size_t nQKV = (size_t)BB * SS * DD;
  short* qa_bf   = (short*)alloc(nQKV * 2);
  short* ma_bf   = (short*)alloc(nQKV * 2);
  short* bias_bk = (short*)alloc((size_t)BB * SS * SS * 2);
  short* Wqt  = (short*)alloc((size_t)DD * DD * 2);
  short* Wkvt = (short*)alloc((size_t)2 * DD * DD * 2);
  short* Wot  = (short*)alloc((size_t)DD * DD * 2);
  short* Qp   = (short*)alloc(nQKV * 2);
  short* KVp  = (short*)alloc(nQKV * 2 * 2);
  short* AOp  = (short*)alloc(nQKV * 2);
  short* VTp  = qa_bf;  // reuse: qa_bf dead after Q-projection GEMM

  const float LOG2E = 1.4426950408889634f;
  int n4a = (int)(nQKV / 4);
  cvt_kernel<<<(n4a + 255) / 256, 256, 0, stream>>>(qa, qa_bf, n4a, 1.0f);
  cvt_kernel<<<(n4a + 255) / 256, 256, 0, stream>>>(ma, ma_bf, n4a, 1.0f);

  btrans_blk<<<dim3(SS / 64, SS / 64, BB), 256, 0, stream>>>(bias, bias_bk, LOG2E);

  dim3 tg(64, 64);
  wtrans_kernel<<<tg, 256, 0, stream>>>(Wq, Wqt, 0.125f * LOG2E);
  wtrans_kernel<<<tg, 256, 0, stream>>>(Wk, Wkvt, 1.0f);
  wtrans_kernel<<<tg, 256, 0, stream>>>(Wv, Wkvt + (size_t)DD * DD, 1.0f);
  wtrans_kernel<<<tg, 256, 0, stream>>>(Wo, Wot, 1.0f);

  gemm_kernel<0><<<BB * SS / 128 * (DD / 128), 256, 0, stream>>>(qa_bf, Wqt, Qp, BB * SS, DD, DD);
  gemm_kernel<0><<<BB * SS / 128 * (2 * DD / 128), 256, 0, stream>>>(ma_bf, Wkvt, KVp, BB * SS, 2 * DD, DD);

  vtrans_kernel<<<dim3(SS / 64, DD / 64, BB), 256, 0, stream>>>(KVp + DD, VTp, 2 * DD);

  attn_kernel<<<BB * HH * (SS / 128), 256, 0, stream>>>(Qp, KVp, VTp, bias_bk, AOp, 2 * DD);

  gemm_kernel<1><<<BB * SS / 128 * (DD / 128), 256, 0, stream>>>(AOp, Wot, out, BB * SS, DD, DD);
}

// Round 13
// 264.836 us; speedup vs baseline: 1.2181x; 1.0558x over previous
//
#include <hip/hip_runtime.h>
#include <hip/hip_bf16.h>

#define BB 4
#define SS 2048
#define DD 1024
#define HH 16
#define DHH 64

typedef __attribute__((ext_vector_type(8))) short short8;
typedef __attribute__((ext_vector_type(4))) float floatx4;
typedef __attribute__((ext_vector_type(16))) float floatx16;
typedef __attribute__((ext_vector_type(4))) int int4v;

__device__ inline short f2bf(float x) {
  union { float f; unsigned u; } v; v.f = x;
  unsigned r = v.u + 0x7FFFu + ((v.u >> 16) & 1u);
  return (short)(r >> 16);
}
__device__ inline float bf2f(short x) {
  union { unsigned u; float f; } v;
  v.u = ((unsigned)(unsigned short)x) << 16;
  return v.f;
}
__device__ inline int cvtpk(float lo, float hi) {
  int r;
  asm("v_cvt_pk_bf16_f32 %0, %1, %2" : "=v"(r) : "v"(lo), "v"(hi));
  return r;
}
// DST[63:32] <-> SRC[31:0]
__device__ inline void pl32swap(int& a, int& b) {
  asm("v_permlane32_swap_b32 %0, %1" : "+v"(a), "+v"(b));
}

typedef __attribute__((address_space(1))) const unsigned int GUI;
typedef __attribute__((address_space(3))) unsigned int LUI;
__device__ inline void gload16(const void* g, void* l) {
  __builtin_amdgcn_global_load_lds((GUI*)g, (LUI*)l, 16, 0, 0);
}

// ---------------- fused f32 -> bf16 conversion for qa+ma (contiguous outs) ------
__global__ __launch_bounds__(256) void cvt2_kernel(const float* __restrict__ in0,
                                                   const float* __restrict__ in1,
                                                   short* __restrict__ out, int n4half) {
  int i = blockIdx.x * 256 + threadIdx.x;
  if (i >= 2 * n4half) return;
  const float* src = (i < n4half) ? in0 : in1;
  int j = (i < n4half) ? i : i - n4half;
  float4 v = ((const float4*)src)[j];
  short4 o;
  o.x = f2bf(v.x); o.y = f2bf(v.y); o.z = f2bf(v.z); o.w = f2bf(v.w);
  ((short4*)out)[i] = o;
}

// ---------------- weight transpose + convert, all 4 weights in one dispatch -----
__global__ __launch_bounds__(256) void wtrans4_kernel(const float* __restrict__ W0,
                                                      const float* __restrict__ W1,
                                                      const float* __restrict__ W2,
                                                      const float* __restrict__ W3,
                                                      short* __restrict__ o0,
                                                      short* __restrict__ o1,
                                                      short* __restrict__ o2,
                                                      short* __restrict__ o3,
                                                      float s0) {
  __shared__ float tile[16][17];
  const int z = blockIdx.z;
  const float* in = (z == 0) ? W0 : (z == 1) ? W1 : (z == 2) ? W2 : W3;
  short* out = (z == 0) ? o0 : (z == 1) ? o1 : (z == 2) ? o2 : o3;
  const float scale = (z == 0) ? s0 : 1.0f;
  int tx = threadIdx.x & 15, ty = threadIdx.x >> 4;
  int k = blockIdx.y * 16 + ty;
  int n = blockIdx.x * 16 + tx;
  tile[ty][tx] = in[(size_t)k * 1024 + n];
  __syncthreads();
  int n2 = blockIdx.x * 16 + ty;
  int k2 = blockIdx.y * 16 + tx;
  out[(size_t)n2 * 1024 + k2] = f2bf(tile[tx][ty] * scale);
}

// ---------------- bias -> blocked bf16 layout (64-kv tiles) -------------------
// out[((b*32+kvtile)*16 + s)*8192 + q*4 + j] = bias[b][q][kvtile*64 + kvt*32+8g+4hi+j]
// where s = kvt*8 + g*2 + hi.
__global__ __launch_bounds__(256) void btrans_blk(const float* __restrict__ in,
                                                  short* __restrict__ out, float scale) {
  __shared__ short tile[64][68];
  const int t = threadIdx.x;
  const int b = blockIdx.z;
  const int q0 = blockIdx.x * 64, kv0 = blockIdx.y * 64;
  const float* gin = in + ((size_t)b * SS + q0) * SS + kv0;
#pragma unroll
  for (int i = 0; i < 4; ++i) {
    int idx = t + 256 * i;
    int row = idx >> 4, c4 = idx & 15;
    float4 v = ((const float4*)(gin + (size_t)row * SS))[c4];
    tile[row][c4 * 4 + 0] = f2bf(v.x * scale);
    tile[row][c4 * 4 + 1] = f2bf(v.y * scale);
    tile[row][c4 * 4 + 2] = f2bf(v.z * scale);
    tile[row][c4 * 4 + 3] = f2bf(v.w * scale);
  }
  __syncthreads();
  short* gout = out + (size_t)((b * 32 + (kv0 >> 6)) * 16) * 8192 + (size_t)q0 * 4;
#pragma unroll
  for (int i = 0; i < 4; ++i) {
    int idx = t + 256 * i;
    int s = idx >> 6, ql = idx & 63;
    int kvt = s >> 3, g = (s >> 1) & 3, hi = s & 1;
    short4 v = *(const short4*)&tile[ql][kvt * 32 + g * 8 + hi * 4];
    *(short4*)&gout[(size_t)s * 8192 + (size_t)ql * 4] = v;
  }
}

// ---------------- V transpose: [B][S][ldin] cols 0..1023 -> [B][1024][S] --------
__global__ __launch_bounds__(256) void vtrans_kernel(const short* __restrict__ in,
                                                     short* __restrict__ out, int ldin) {
  __shared__ int tile[64][33];
  const int t = threadIdx.x;
  const int b = blockIdx.z;
  const int s0 = blockIdx.x * 64, d0 = blockIdx.y * 64;
  const int* gin = (const int*)(in + (size_t)b * SS * ldin);
  const int ldi2 = ldin >> 1;
  int* gout = (int*)(out + (size_t)b * DD * SS);
#pragma unroll
  for (int i = 0; i < 8; ++i) {
    int idx = t + i * 256;
    int row = idx >> 5, col = idx & 31;
    tile[row][col] = gin[(size_t)(s0 + row) * ldi2 + (d0 >> 1) + col];
  }
  __syncthreads();
#pragma unroll
  for (int i = 0; i < 8; ++i) {
    int idx = t + i * 256;
    int d = idx >> 5, spc = idx & 31;
    int a = tile[2 * spc][d >> 1];
    int c = tile[2 * spc + 1][d >> 1];
    int o = (d & 1) ? (((a >> 16) & 0xffff) | (c & 0xffff0000))
                    : ((a & 0xffff) | (c << 16));
    gout[(size_t)(d0 + d) * (SS / 2) + (s0 >> 1) + spc] = o;
  }
}

// ---------------- bf16 MFMA GEMM, dbuf 2-phase, XCD-swizzled, T2 LDS swizzle ----
// Tile TM x 128, TM in {64,128}. TM=64 doubles block count for narrow-N GEMMs
// (Q/O: N=1024 -> grid 1024 = 4 blocks/CU instead of 2).
template<int OUT_F32, int TM>
__global__ __launch_bounds__(256) void gemm_kernel(const short* __restrict__ A,
                                                   const short* __restrict__ Bt,
                                                   void* __restrict__ Cout,
                                                   int M, int N, int K) {
  constexpr int MI = TM / 32;   // A-frags per wave: 128 -> 4, 64 -> 2
  __shared__ alignas(16) short As[2][TM][32];
  __shared__ alignas(16) short Bs[2][128][32];
  const int t = threadIdx.x;
  const int lane = t & 63, wave = t >> 6;
  const int wr = wave >> 1, wc = wave & 1;
  const int l15 = lane & 15, l4 = lane >> 4;

  const int hw = blockIdx.x;
  const int L = (hw & 7) * ((int)gridDim.x >> 3) + (hw >> 3);
  const int NY = N >> 7;
  const int bxm = L / NY, byn = L % NY;

  floatx4 acc[MI][4];
#pragma unroll
  for (int i = 0; i < MI; ++i)
#pragma unroll
    for (int j = 0; j < 4; ++j) acc[i][j] = (floatx4){0.f, 0.f, 0.f, 0.f};

  const short* Ag = A + (size_t)bxm * TM * K;
  const short* Bg = Bt + (size_t)byn * 128 * K;
  const int o0 = t * 16, o1 = t * 16 + 4096;
  const int r0 = o0 >> 6, r1 = o1 >> 6;
  const int c0 = (((o0 >> 1) & 31) ^ ((r0 & 3) << 3));
  const int c1 = (((o1 >> 1) & 31) ^ ((r1 & 3) << 3));
  const int rbase = wr * (TM / 2) + l15;
  const int cbase = wc * 64 + l15;
  const int koff = (l4 ^ (l15 & 3)) * 8;

#define GSTAGE(buf, k0)                                                    \
  {                                                                        \
    gload16(&Ag[(size_t)r0 * K + (k0) + c0], (char*)As[buf] + o0);         \
    if (TM == 128)                                                         \
      gload16(&Ag[(size_t)r1 * K + (k0) + c1], (char*)As[buf] + o1);       \
    gload16(&Bg[(size_t)r0 * K + (k0) + c0], (char*)Bs[buf] + o0);         \
    gload16(&Bg[(size_t)r1 * K + (k0) + c1], (char*)Bs[buf] + o1);         \
  }

  GSTAGE(0, 0)
  __syncthreads();
  int cur = 0;
  for (int k0 = 0; k0 < K; k0 += 32) {
    if (k0 + 32 < K) { GSTAGE(cur ^ 1, k0 + 32) }
    short8 af[MI], bfr[4];
#pragma unroll
    for (int mi = 0; mi < MI; ++mi) af[mi] = *(const short8*)&As[cur][rbase + mi * 16][koff];
#pragma unroll
    for (int ni = 0; ni < 4; ++ni) bfr[ni] = *(const short8*)&Bs[cur][cbase + ni * 16][koff];
    __builtin_amdgcn_s_setprio(1);
#pragma unroll
    for (int mi = 0; mi < MI; ++mi)
#pragma unroll
      for (int ni = 0; ni < 4; ++ni)
        acc[mi][ni] = __builtin_amdgcn_mfma_f32_16x16x32_bf16(af[mi], bfr[ni], acc[mi][ni], 0, 0, 0);
    __builtin_amdgcn_s_setprio(0);
    __syncthreads();
    cur ^= 1;
  }
#undef GSTAGE

  const int row0 = bxm * TM + wr * (TM / 2) + l4 * 4;
  const int col0 = byn * 128 + wc * 64 + l15;
  if (OUT_F32) {
    float* Cf = (float*)Cout;
#pragma unroll
    for (int mi = 0; mi < MI; ++mi)
#pragma unroll
      for (int ni = 0; ni < 4; ++ni)
#pragma unroll
        for (int r = 0; r < 4; ++r)
          Cf[(size_t)(row0 + mi * 16 + r) * N + col0 + ni * 16] = acc[mi][ni][r];
  } else {
    short* Cs = (short*)Cout;
#pragma unroll
    for (int mi = 0; mi < MI; ++mi)
#pragma unroll
      for (int ni = 0; ni < 4; ++ni)
#pragma unroll
        for (int r = 0; r < 4; ++r)
          Cs[(size_t)(row0 + mi * 16 + r) * N + col0 + ni * 16] = f2bf(acc[mi][ni][r]);
  }
}

// ---------------- flash attention: no-max log2 softmax, VALU row-sum -----------
// (unchanged from round 12: 107 us, 96 total regs, 4 waves/SIMD)
__global__ __launch_bounds__(256, 4) void attn_kernel(const short* __restrict__ Q,
                                                      const short* __restrict__ K,
                                                      const short* __restrict__ VT,
                                                      const short* __restrict__ bias_blk,
                                                      short* __restrict__ O, int ldk) {
  __shared__ alignas(16) short Klds[2][64][64];      // 16KB
  __shared__ alignas(16) short Vtl[2][64][64];       // 16KB

  const int t = threadIdx.x;
  const int lane = t & 63, wave = t >> 6;
  const int hw = blockIdx.x;
  const int L = (hw & 7) * 128 + (hw >> 3);
  const int bh = L >> 4;
  const int q0 = (L & 15) * 128;
  const int b = bh >> 4, h = bh & 15;
  const int l31 = lane & 31, hi = lane >> 5;

  const short* Qb = Q + (size_t)b * SS * DD + h * DHH;
  const short* Kb = K + (size_t)b * SS * ldk + h * DHH;
  const short* VTb = VT + ((size_t)b * DD + h * DHH) * SS;
  const short* Bl = bias_blk + (size_t)(b * 32 * 16) * 8192 + (size_t)hi * 8192
                    + (size_t)(q0 + wave * 32 + l31) * 4;

  const int sr0 = t >> 3;
  const int scb = ((t & 7) ^ (sr0 & 7)) * 8;

#define STAGE_KV(buf, kvb)                                                              \
  {                                                                                     \
    gload16(&Kb[(size_t)((kvb) + sr0) * ldk + scb], (char*)&Klds[buf][0][0] + t * 16);  \
    gload16(&Kb[(size_t)((kvb) + sr0 + 32) * ldk + scb],                                \
            (char*)&Klds[buf][0][0] + 4096 + t * 16);                                   \
    gload16(&VTb[(size_t)sr0 * SS + (kvb) + scb], (char*)&Vtl[buf][0][0] + t * 16);     \
    gload16(&VTb[(size_t)(sr0 + 32) * SS + (kvb) + scb],                                \
            (char*)&Vtl[buf][0][0] + 4096 + t * 16);                                    \
  }
#define BIAS_PREF(kvb)                                                                  \
  {                                                                                     \
    int kt16 = ((kvb) >> 6) << 4;                                                       \
    _Pragma("unroll")                                                                   \
    for (int kvt = 0; kvt < 2; ++kvt)                                                   \
      _Pragma("unroll")                                                                 \
      for (int g = 0; g < 4; ++g)                                                       \
        br[kvt * 4 + g] = *(const short4*)&Bl[(size_t)(kt16 + kvt * 8 + g * 2) * 8192]; \
  }

  short4 br[8];
  STAGE_KV(0, 0)
  BIAS_PREF(0)

  const int q = wave * 32 + l31;
  short8 qf[4];
  {
    int qrow = q0 + q;
#pragma unroll
    for (int dc = 0; dc < 4; ++dc)
      qf[dc] = *(const short8*)&Qb[(size_t)qrow * DD + dc * 16 + hi * 8];
  }

  floatx16 acc_pv[2];
#pragma unroll
  for (int r = 0; r < 16; ++r) { acc_pv[0][r] = 0.f; acc_pv[1][r] = 0.f; }
  float psum = 0.f;

  __syncthreads();
  int cur = 0;
  for (int kv0 = 0; kv0 < SS; kv0 += 64) {
    if (kv0 + 64 < SS) STAGE_KV(cur ^ 1, kv0 + 64)

#pragma unroll
    for (int kvt = 0; kvt < 2; ++kvt) {
      floatx16 c_;
#pragma unroll
      for (int g = 0; g < 4; ++g) {
        short4 b4 = br[kvt * 4 + g];
        c_[4 * g + 0] = bf2f(b4.x); c_[4 * g + 1] = bf2f(b4.y);
        c_[4 * g + 2] = bf2f(b4.z); c_[4 * g + 3] = bf2f(b4.w);
      }
      int kr = kvt * 32 + l31;
      __builtin_amdgcn_s_setprio(1);
#pragma unroll
      for (int dc = 0; dc < 4; ++dc) {
        short8 kf = *(const short8*)&Klds[cur][kr][((2 * dc + hi) ^ (kr & 7)) * 8];
        c_ = __builtin_amdgcn_mfma_f32_32x32x16_bf16(kf, qf[dc], c_, 0, 0, 0);
      }
      __builtin_amdgcn_s_setprio(0);

      if (kvt == 1 && kv0 + 64 < SS) BIAS_PREF(kv0 + 64)

      int dd[8];
#pragma unroll
      for (int i = 0; i < 8; ++i) {
        float e0 = __builtin_amdgcn_exp2f(c_[2 * i]);
        float e1 = __builtin_amdgcn_exp2f(c_[2 * i + 1]);
        psum += e0 + e1;
        dd[i] = cvtpk(e0, e1);
      }

#pragma unroll
      for (int ks2 = 0; ks2 < 2; ++ks2) {
        int a0 = dd[4 * ks2 + 0], a1 = dd[4 * ks2 + 1];
        int a2 = dd[4 * ks2 + 2], a3 = dd[4 * ks2 + 3];
        pl32swap(a0, a2);
        pl32swap(a1, a3);
        int4v w; w[0] = a0; w[1] = a1; w[2] = a2; w[3] = a3;
        short8 pf = *(short8*)&w;
        int ks = kvt * 2 + ks2;
        __builtin_amdgcn_s_setprio(1);
#pragma unroll
        for (int dt = 0; dt < 2; ++dt) {
          int vr = dt * 32 + l31;
          short8 vf = *(const short8*)&Vtl[cur][vr][((2 * ks + hi) ^ (vr & 7)) * 8];
          acc_pv[dt] = __builtin_amdgcn_mfma_f32_32x32x16_bf16(vf, pf, acc_pv[dt], 0, 0, 0);
        }
        __builtin_amdgcn_s_setprio(0);
      }
    }
    __syncthreads();
    cur ^= 1;
  }
#undef STAGE_KV
#undef BIAS_PREF

  float ssum = psum + __shfl_xor(psum, 32);
  float inv = 1.0f / ssum;

  short* ep = (short*)Klds + wave * 2048;
#pragma unroll
  for (int dt = 0; dt < 2; ++dt)
#pragma unroll
    for (int r = 0; r < 16; ++r) {
      int d = dt * 32 + (r & 3) + 8 * (r >> 2) + 4 * hi;
      int chunk = d >> 3, doff = d & 7;
      ep[l31 * 64 + ((chunk ^ (l31 & 7)) << 3) + doff] = f2bf(acc_pv[dt][r] * inv);
    }
  short* Ob = O + (size_t)b * SS * DD + h * DHH;
  const int rr = lane >> 3, cc = lane & 7;
#pragma unroll
  for (int ii = 0; ii < 4; ++ii) {
    int q2 = ii * 8 + rr;
    short8 vv = *(const short8*)&ep[q2 * 64 + ((cc ^ (q2 & 7)) << 3)];
    *(short8*)&Ob[(size_t)(q0 + wave * 32 + q2) * DD + cc * 8] = vv;
  }
}

// ---------------- launch ----------------
extern "C" void kernel_launch(void* const* d_in, const int* in_sizes, int n_in,
                              void* d_out, int out_size, void* d_ws, size_t ws_size,
                              hipStream_t stream) {
  const float* qa   = (const float*)d_in[0];
  const float* ma   = (const float*)d_in[1];
  const float* bias = (const float*)d_in[2];
  const float* Wq   = (const float*)d_in[3];
  const float* Wk   = (const float*)d_in[4];
  const float* Wv   = (const float*)d_in[5];
  const float* Wo   = (const float*)d_in[6];
  float* out = (float*)d_out;

  char* ws = (char*)d_ws;
  size_t off = 0;
  auto alloc = [&](size_t bytes) {
    char* p = ws + off;
    off += (bytes + 255) & ~(size_t)255;
    return p;
  };
  const size_t nQKV = (size_t)BB * SS * DD;
  short* qa_bf   = (short*)alloc(nQKV * 2);
  short* ma_bf   = (short*)alloc(nQKV * 2);   // contiguous after qa_bf
  short* bias_bk = (short*)alloc((size_t)BB * SS * SS * 2);
  short* Wqt  = (short*)alloc((size_t)DD * DD * 2);
  short* Wkvt = (short*)alloc((size_t)2 * DD * DD * 2);
  short* Wot  = (short*)alloc((size_t)DD * DD * 2);
  short* Qp   = (short*)alloc(nQKV * 2);
  short* KVp  = (short*)alloc(nQKV * 2 * 2);
  short* AOp  = (short*)alloc(nQKV * 2);
  short* VTp  = qa_bf;  // reuse: qa_bf dead after Q-projection GEMM

  const float LOG2E = 1.4426950408889634f;
  int n4a = (int)(nQKV / 4);
  cvt2_kernel<<<(2 * n4a + 255) / 256, 256, 0, stream>>>(qa, ma, qa_bf, n4a);

  btrans_blk<<<dim3(SS / 64, SS / 64, BB), 256, 0, stream>>>(bias, bias_bk, LOG2E);

  wtrans4_kernel<<<dim3(64, 64, 4), 256, 0, stream>>>(
      Wq, Wk, Wv, Wo, Wqt, Wkvt, Wkvt + (size_t)DD * DD, Wot, 0.125f * LOG2E);

  gemm_kernel<0, 64><<<BB * SS / 64 * (DD / 128), 256, 0, stream>>>(qa_bf, Wqt, Qp, BB * SS, DD, DD);
  gemm_kernel<0, 128><<<BB * SS / 128 * (2 * DD / 128), 256, 0, stream>>>(ma_bf, Wkvt, KVp, BB * SS, 2 * DD, DD);

  vtrans_kernel<<<dim3(SS / 64, DD / 64, BB), 256, 0, stream>>>(KVp + DD, VTp, 2 * DD);

  attn_kernel<<<BB * HH * (SS / 128), 256, 0, stream>>>(Qp, KVp, VTp, bias_bk, AOp, 2 * DD);

  gemm_kernel<1, 64><<<BB * SS / 64 * (DD / 128), 256, 0, stream>>>(AOp, Wot, out, BB * SS, DD, DD);
}

// Round 14
// 245.312 us; speedup vs baseline: 1.3150x; 1.0796x over previous
//
#include <hip/hip_runtime.h>
#include <hip/hip_bf16.h>

#define BB 4
#define SS 2048
#define DD 1024
#define HH 16
#define DHH 64

typedef __attribute__((ext_vector_type(8))) short short8;
typedef __attribute__((ext_vector_type(4))) float floatx4;
typedef __attribute__((ext_vector_type(16))) float floatx16;
typedef __attribute__((ext_vector_type(4))) int int4v;

__device__ inline short f2bf(float x) {
  union { float f; unsigned u; } v; v.f = x;
  unsigned r = v.u + 0x7FFFu + ((v.u >> 16) & 1u);
  return (short)(r >> 16);
}
__device__ inline float bf2f(short x) {
  union { unsigned u; float f; } v;
  v.u = ((unsigned)(unsigned short)x) << 16;
  return v.f;
}
__device__ inline int cvtpk(float lo, float hi) {
  int r;
  asm("v_cvt_pk_bf16_f32 %0, %1, %2" : "=v"(r) : "v"(lo), "v"(hi));
  return r;
}
// DST[63:32] <-> SRC[31:0]
__device__ inline void pl32swap(int& a, int& b) {
  asm("v_permlane32_swap_b32 %0, %1" : "+v"(a), "+v"(b));
}

typedef __attribute__((address_space(1))) const unsigned int GUI;
typedef __attribute__((address_space(3))) unsigned int LUI;
__device__ inline void gload16(const void* g, void* l) {
  __builtin_amdgcn_global_load_lds((GUI*)g, (LUI*)l, 16, 0, 0);
}

// ---------------- fused prep: cvt(qa,ma) + wtrans x4 + btrans, one dispatch -----
// blocks [0,16384): qa/ma f32->bf16 (contiguous out)
// blocks [16384,32768): weight transpose+cvt (z = (blk-16384)>>12)
// blocks [32768,36864): bias -> blocked bf16 layout (z = (blk-32768)>>10)
__global__ __launch_bounds__(256) void prep_kernel(
    const float* __restrict__ qa, const float* __restrict__ ma,
    const float* __restrict__ bias,
    const float* __restrict__ W0, const float* __restrict__ W1,
    const float* __restrict__ W2, const float* __restrict__ W3,
    short* __restrict__ qm_bf, short* __restrict__ bias_bk,
    short* __restrict__ Wqt, short* __restrict__ Wkvt, short* __restrict__ Wot,
    float wqscale, float bscale) {
  __shared__ alignas(16) char smemraw[8704];
  const int blk = blockIdx.x;
  const int t = threadIdx.x;
  if (blk < 16384) {
    // ---- cvt2 ----
    int i = blk * 256 + t;
    const int n4half = (BB * SS * DD) / 4;
    const float* src = (i < n4half) ? qa : ma;
    int j = (i < n4half) ? i : i - n4half;
    float4 v = ((const float4*)src)[j];
    short4 o;
    o.x = f2bf(v.x); o.y = f2bf(v.y); o.z = f2bf(v.z); o.w = f2bf(v.w);
    ((short4*)qm_bf)[i] = o;
  } else if (blk < 32768) {
    // ---- wtrans ----
    float(*tile)[17] = (float(*)[17])smemraw;
    int jj = blk - 16384;
    int z = jj >> 12, rem = jj & 4095;
    int by = rem >> 6, bx = rem & 63;
    const float* in = (z == 0) ? W0 : (z == 1) ? W1 : (z == 2) ? W2 : W3;
    short* out = (z == 0) ? Wqt : (z == 1) ? Wkvt
                 : (z == 2) ? (Wkvt + (size_t)DD * DD) : Wot;
    const float scale = (z == 0) ? wqscale : 1.0f;
    int tx = t & 15, ty = t >> 4;
    int k = by * 16 + ty;
    int n = bx * 16 + tx;
    tile[ty][tx] = in[(size_t)k * 1024 + n];
    __syncthreads();
    int n2 = bx * 16 + ty;
    int k2 = by * 16 + tx;
    out[(size_t)n2 * 1024 + k2] = f2bf(tile[tx][ty] * scale);
  } else {
    // ---- btrans: out[((b*32+kvtile)*16 + kvt*8+g*2+hi)*8192 + q*4 + j] ----
    short(*tile)[68] = (short(*)[68])smemraw;
    int jj = blk - 32768;
    int b = jj >> 10, rem = jj & 1023;
    int by = rem >> 5, bx = rem & 31;
    int q0 = bx * 64, kv0 = by * 64;
    const float* gin = bias + ((size_t)b * SS + q0) * SS + kv0;
#pragma unroll
    for (int i = 0; i < 4; ++i) {
      int idx = t + 256 * i;
      int row = idx >> 4, c4 = idx & 15;
      float4 v = ((const float4*)(gin + (size_t)row * SS))[c4];
      tile[row][c4 * 4 + 0] = f2bf(v.x * bscale);
      tile[row][c4 * 4 + 1] = f2bf(v.y * bscale);
      tile[row][c4 * 4 + 2] = f2bf(v.z * bscale);
      tile[row][c4 * 4 + 3] = f2bf(v.w * bscale);
    }
    __syncthreads();
    short* gout = bias_bk + (size_t)((b * 32 + (kv0 >> 6)) * 16) * 8192 + (size_t)q0 * 4;
#pragma unroll
    for (int i = 0; i < 4; ++i) {
      int idx = t + 256 * i;
      int s = idx >> 6, ql = idx & 63;
      int kvt = s >> 3, g = (s >> 1) & 3, hi = s & 1;
      short4 v = *(const short4*)&tile[ql][kvt * 32 + g * 8 + hi * 4];
      *(short4*)&gout[(size_t)s * 8192 + (size_t)ql * 4] = v;
    }
  }
}

// ---------------- bf16 MFMA GEMM (Q/O), dbuf 2-phase, XCD + T2 swizzle ---------
// Tile TM x 128, TM in {64,128}.
template<int OUT_F32, int TM>
__global__ __launch_bounds__(256) void gemm_kernel(const short* __restrict__ A,
                                                   const short* __restrict__ Bt,
                                                   void* __restrict__ Cout,
                                                   int M, int N, int K) {
  constexpr int MI = TM / 32;
  __shared__ alignas(16) short As[2][TM][32];
  __shared__ alignas(16) short Bs[2][128][32];
  const int t = threadIdx.x;
  const int lane = t & 63, wave = t >> 6;
  const int wr = wave >> 1, wc = wave & 1;
  const int l15 = lane & 15, l4 = lane >> 4;

  const int hw = blockIdx.x;
  const int L = (hw & 7) * ((int)gridDim.x >> 3) + (hw >> 3);
  const int NY = N >> 7;
  const int bxm = L / NY, byn = L % NY;

  floatx4 acc[MI][4];
#pragma unroll
  for (int i = 0; i < MI; ++i)
#pragma unroll
    for (int j = 0; j < 4; ++j) acc[i][j] = (floatx4){0.f, 0.f, 0.f, 0.f};

  const short* Ag = A + (size_t)bxm * TM * K;
  const short* Bg = Bt + (size_t)byn * 128 * K;
  const int o0 = t * 16, o1 = t * 16 + 4096;
  const int r0 = o0 >> 6, r1 = o1 >> 6;
  const int c0 = (((o0 >> 1) & 31) ^ ((r0 & 3) << 3));
  const int c1 = (((o1 >> 1) & 31) ^ ((r1 & 3) << 3));
  const int rbase = wr * (TM / 2) + l15;
  const int cbase = wc * 64 + l15;
  const int koff = (l4 ^ (l15 & 3)) * 8;

#define GSTAGE(buf, k0)                                                    \
  {                                                                        \
    gload16(&Ag[(size_t)r0 * K + (k0) + c0], (char*)As[buf] + o0);         \
    if (TM == 128)                                                         \
      gload16(&Ag[(size_t)r1 * K + (k0) + c1], (char*)As[buf] + o1);       \
    gload16(&Bg[(size_t)r0 * K + (k0) + c0], (char*)Bs[buf] + o0);         \
    gload16(&Bg[(size_t)r1 * K + (k0) + c1], (char*)Bs[buf] + o1);         \
  }

  GSTAGE(0, 0)
  __syncthreads();
  int cur = 0;
  for (int k0 = 0; k0 < K; k0 += 32) {
    if (k0 + 32 < K) { GSTAGE(cur ^ 1, k0 + 32) }
    short8 af[MI], bfr[4];
#pragma unroll
    for (int mi = 0; mi < MI; ++mi) af[mi] = *(const short8*)&As[cur][rbase + mi * 16][koff];
#pragma unroll
    for (int ni = 0; ni < 4; ++ni) bfr[ni] = *(const short8*)&Bs[cur][cbase + ni * 16][koff];
    __builtin_amdgcn_s_setprio(1);
#pragma unroll
    for (int mi = 0; mi < MI; ++mi)
#pragma unroll
      for (int ni = 0; ni < 4; ++ni)
        acc[mi][ni] = __builtin_amdgcn_mfma_f32_16x16x32_bf16(af[mi], bfr[ni], acc[mi][ni], 0, 0, 0);
    __builtin_amdgcn_s_setprio(0);
    __syncthreads();
    cur ^= 1;
  }
#undef GSTAGE

  const int row0 = bxm * TM + wr * (TM / 2) + l4 * 4;
  const int col0 = byn * 128 + wc * 64 + l15;
  if (OUT_F32) {
    float* Cf = (float*)Cout;
#pragma unroll
    for (int mi = 0; mi < MI; ++mi)
#pragma unroll
      for (int ni = 0; ni < 4; ++ni)
#pragma unroll
        for (int r = 0; r < 4; ++r)
          Cf[(size_t)(row0 + mi * 16 + r) * N + col0 + ni * 16] = acc[mi][ni][r];
  } else {
    short* Cs = (short*)Cout;
#pragma unroll
    for (int mi = 0; mi < MI; ++mi)
#pragma unroll
      for (int ni = 0; ni < 4; ++ni)
#pragma unroll
        for (int r = 0; r < 4; ++r)
          Cs[(size_t)(row0 + mi * 16 + r) * N + col0 + ni * 16] = f2bf(acc[mi][ni][r]);
  }
}

// ---------------- KV GEMM with fused V^T epilogue ------------------------------
// A[B*S][1024] @ Wkvt[2048][1024]^T. N-tiles 0-7 -> K (dense [B*S][1024]);
// N-tiles 8-15 -> V, transposed in-LDS and stored to VT[b][1024][2048].
__global__ __launch_bounds__(256) void gemm_kv(const short* __restrict__ A,
                                               const short* __restrict__ Bt,
                                               short* __restrict__ Kp,
                                               short* __restrict__ VT, int K) {
  __shared__ alignas(16) short smem[16384];   // 32KB: As | Bs, reused as V^T tile
  short (*As)[128][32] = (short(*)[128][32])smem;
  short (*Bs)[128][32] = (short(*)[128][32])(smem + 8192);
  const int t = threadIdx.x;
  const int lane = t & 63, wave = t >> 6;
  const int wr = wave >> 1, wc = wave & 1;
  const int l15 = lane & 15, l4 = lane >> 4;

  const int hw = blockIdx.x;
  const int L = (hw & 7) * ((int)gridDim.x >> 3) + (hw >> 3);
  const int bxm = L >> 4, byn = L & 15;

  floatx4 acc[4][4];
#pragma unroll
  for (int i = 0; i < 4; ++i)
#pragma unroll
    for (int j = 0; j < 4; ++j) acc[i][j] = (floatx4){0.f, 0.f, 0.f, 0.f};

  const short* Ag = A + (size_t)bxm * 128 * K;
  const short* Bg = Bt + (size_t)byn * 128 * K;
  const int o0 = t * 16, o1 = t * 16 + 4096;
  const int r0 = o0 >> 6, r1 = o1 >> 6;
  const int c0 = (((o0 >> 1) & 31) ^ ((r0 & 3) << 3));
  const int c1 = (((o1 >> 1) & 31) ^ ((r1 & 3) << 3));
  const int rbase = wr * 64 + l15;
  const int cbase = wc * 64 + l15;
  const int koff = (l4 ^ (l15 & 3)) * 8;

#define GSTAGE(buf, k0)                                                     \
  {                                                                         \
    gload16(&Ag[(size_t)r0 * K + (k0) + c0], (char*)As[buf] + o0);          \
    gload16(&Ag[(size_t)r1 * K + (k0) + c1], (char*)As[buf] + o1);          \
    gload16(&Bg[(size_t)r0 * K + (k0) + c0], (char*)Bs[buf] + o0);          \
    gload16(&Bg[(size_t)r1 * K + (k0) + c1], (char*)Bs[buf] + o1);          \
  }

  GSTAGE(0, 0)
  __syncthreads();
  int cur = 0;
  for (int k0 = 0; k0 < K; k0 += 32) {
    if (k0 + 32 < K) { GSTAGE(cur ^ 1, k0 + 32) }
    short8 af[4], bfr[4];
#pragma unroll
    for (int mi = 0; mi < 4; ++mi) af[mi] = *(const short8*)&As[cur][rbase + mi * 16][koff];
#pragma unroll
    for (int ni = 0; ni < 4; ++ni) bfr[ni] = *(const short8*)&Bs[cur][cbase + ni * 16][koff];
    __builtin_amdgcn_s_setprio(1);
#pragma unroll
    for (int mi = 0; mi < 4; ++mi)
#pragma unroll
      for (int ni = 0; ni < 4; ++ni)
        acc[mi][ni] = __builtin_amdgcn_mfma_f32_16x16x32_bf16(af[mi], bfr[ni], acc[mi][ni], 0, 0, 0);
    __builtin_amdgcn_s_setprio(0);
    __syncthreads();
    cur ^= 1;
  }
#undef GSTAGE

  if (byn < 8) {
    // K half: dense [B*S][1024] output
    const int row0 = bxm * 128 + wr * 64 + l4 * 4;
    const int col0 = byn * 128 + wc * 64 + l15;
#pragma unroll
    for (int mi = 0; mi < 4; ++mi)
#pragma unroll
      for (int ni = 0; ni < 4; ++ni)
#pragma unroll
        for (int r = 0; r < 4; ++r)
          Kp[(size_t)(row0 + mi * 16 + r) * 1024 + col0 + ni * 16] = f2bf(acc[mi][ni][r]);
  } else {
    // V half: transpose via LDS, store VT[b][d][s]
    // (loop above ended with __syncthreads -> staging buffers dead)
    short* tl = smem;   // flat [128 d][128 s], s-chunk swizzled by d&7
#pragma unroll
    for (int mi = 0; mi < 4; ++mi)
#pragma unroll
      for (int ni = 0; ni < 4; ++ni)
#pragma unroll
        for (int r = 0; r < 4; ++r) {
          int srow = wr * 64 + mi * 16 + l4 * 4 + r;
          int dcol = wc * 64 + ni * 16 + l15;
          tl[dcol * 128 + (srow ^ ((dcol & 7) << 3))] = f2bf(acc[mi][ni][r]);
        }
    __syncthreads();
    const int b = bxm >> 4;
    const int s0 = (bxm & 15) * 128;
    const int d0 = (byn - 8) * 128;
    short* Vb = VT + ((size_t)b * DD + d0) * SS + s0;
#pragma unroll
    for (int i = 0; i < 8; ++i) {
      int ci = t + 256 * i;
      int dr = ci >> 4, c = ci & 15;
      short8 v = *(const short8*)&tl[dr * 128 + ((c ^ (dr & 7)) << 3)];
      *(short8*)&Vb[(size_t)dr * SS + c * 8] = v;
    }
  }
}

// ---------------- flash attention: no-max log2 softmax, VALU row-sum -----------
// (unchanged from round 12/13: 107 us; K now dense with ldk=1024)
__global__ __launch_bounds__(256, 4) void attn_kernel(const short* __restrict__ Q,
                                                      const short* __restrict__ K,
                                                      const short* __restrict__ VT,
                                                      const short* __restrict__ bias_blk,
                                                      short* __restrict__ O, int ldk) {
  __shared__ alignas(16) short Klds[2][64][64];      // 16KB
  __shared__ alignas(16) short Vtl[2][64][64];       // 16KB

  const int t = threadIdx.x;
  const int lane = t & 63, wave = t >> 6;
  const int hw = blockIdx.x;
  const int L = (hw & 7) * 128 + (hw >> 3);
  const int bh = L >> 4;
  const int q0 = (L & 15) * 128;
  const int b = bh >> 4, h = bh & 15;
  const int l31 = lane & 31, hi = lane >> 5;

  const short* Qb = Q + (size_t)b * SS * DD + h * DHH;
  const short* Kb = K + (size_t)b * SS * ldk + h * DHH;
  const short* VTb = VT + ((size_t)b * DD + h * DHH) * SS;
  const short* Bl = bias_blk + (size_t)(b * 32 * 16) * 8192 + (size_t)hi * 8192
                    + (size_t)(q0 + wave * 32 + l31) * 4;

  const int sr0 = t >> 3;
  const int scb = ((t & 7) ^ (sr0 & 7)) * 8;

#define STAGE_KV(buf, kvb)                                                              \
  {                                                                                     \
    gload16(&Kb[(size_t)((kvb) + sr0) * ldk + scb], (char*)&Klds[buf][0][0] + t * 16);  \
    gload16(&Kb[(size_t)((kvb) + sr0 + 32) * ldk + scb],                                \
            (char*)&Klds[buf][0][0] + 4096 + t * 16);                                   \
    gload16(&VTb[(size_t)sr0 * SS + (kvb) + scb], (char*)&Vtl[buf][0][0] + t * 16);     \
    gload16(&VTb[(size_t)(sr0 + 32) * SS + (kvb) + scb],                                \
            (char*)&Vtl[buf][0][0] + 4096 + t * 16);                                    \
  }
#define BIAS_PREF(kvb)                                                                  \
  {                                                                                     \
    int kt16 = ((kvb) >> 6) << 4;                                                       \
    _Pragma("unroll")                                                                   \
    for (int kvt = 0; kvt < 2; ++kvt)                                                   \
      _Pragma("unroll")                                                                 \
      for (int g = 0; g < 4; ++g)                                                       \
        br[kvt * 4 + g] = *(const short4*)&Bl[(size_t)(kt16 + kvt * 8 + g * 2) * 8192]; \
  }

  short4 br[8];
  STAGE_KV(0, 0)
  BIAS_PREF(0)

  const int q = wave * 32 + l31;
  short8 qf[4];
  {
    int qrow = q0 + q;
#pragma unroll
    for (int dc = 0; dc < 4; ++dc)
      qf[dc] = *(const short8*)&Qb[(size_t)qrow * DD + dc * 16 + hi * 8];
  }

  floatx16 acc_pv[2];
#pragma unroll
  for (int r = 0; r < 16; ++r) { acc_pv[0][r] = 0.f; acc_pv[1][r] = 0.f; }
  float psum = 0.f;

  __syncthreads();
  int cur = 0;
  for (int kv0 = 0; kv0 < SS; kv0 += 64) {
    if (kv0 + 64 < SS) STAGE_KV(cur ^ 1, kv0 + 64)

#pragma unroll
    for (int kvt = 0; kvt < 2; ++kvt) {
      floatx16 c_;
#pragma unroll
      for (int g = 0; g < 4; ++g) {
        short4 b4 = br[kvt * 4 + g];
        c_[4 * g + 0] = bf2f(b4.x); c_[4 * g + 1] = bf2f(b4.y);
        c_[4 * g + 2] = bf2f(b4.z); c_[4 * g + 3] = bf2f(b4.w);
      }
      int kr = kvt * 32 + l31;
      __builtin_amdgcn_s_setprio(1);
#pragma unroll
      for (int dc = 0; dc < 4; ++dc) {
        short8 kf = *(const short8*)&Klds[cur][kr][((2 * dc + hi) ^ (kr & 7)) * 8];
        c_ = __builtin_amdgcn_mfma_f32_32x32x16_bf16(kf, qf[dc], c_, 0, 0, 0);
      }
      __builtin_amdgcn_s_setprio(0);

      if (kvt == 1 && kv0 + 64 < SS) BIAS_PREF(kv0 + 64)

      int dd[8];
#pragma unroll
      for (int i = 0; i < 8; ++i) {
        float e0 = __builtin_amdgcn_exp2f(c_[2 * i]);
        float e1 = __builtin_amdgcn_exp2f(c_[2 * i + 1]);
        psum += e0 + e1;
        dd[i] = cvtpk(e0, e1);
      }

#pragma unroll
      for (int ks2 = 0; ks2 < 2; ++ks2) {
        int a0 = dd[4 * ks2 + 0], a1 = dd[4 * ks2 + 1];
        int a2 = dd[4 * ks2 + 2], a3 = dd[4 * ks2 + 3];
        pl32swap(a0, a2);
        pl32swap(a1, a3);
        int4v w; w[0] = a0; w[1] = a1; w[2] = a2; w[3] = a3;
        short8 pf = *(short8*)&w;
        int ks = kvt * 2 + ks2;
        __builtin_amdgcn_s_setprio(1);
#pragma unroll
        for (int dt = 0; dt < 2; ++dt) {
          int vr = dt * 32 + l31;
          short8 vf = *(const short8*)&Vtl[cur][vr][((2 * ks + hi) ^ (vr & 7)) * 8];
          acc_pv[dt] = __builtin_amdgcn_mfma_f32_32x32x16_bf16(vf, pf, acc_pv[dt], 0, 0, 0);
        }
        __builtin_amdgcn_s_setprio(0);
      }
    }
    __syncthreads();
    cur ^= 1;
  }
#undef STAGE_KV
#undef BIAS_PREF

  float ssum = psum + __shfl_xor(psum, 32);
  float inv = 1.0f / ssum;

  short* ep = (short*)Klds + wave * 2048;
#pragma unroll
  for (int dt = 0; dt < 2; ++dt)
#pragma unroll
    for (int r = 0; r < 16; ++r) {
      int d = dt * 32 + (r & 3) + 8 * (r >> 2) + 4 * hi;
      int chunk = d >> 3, doff = d & 7;
      ep[l31 * 64 + ((chunk ^ (l31 & 7)) << 3) + doff] = f2bf(acc_pv[dt][r] * inv);
    }
  short* Ob = O + (size_t)b * SS * DD + h * DHH;
  const int rr = lane >> 3, cc = lane & 7;
#pragma unroll
  for (int ii = 0; ii < 4; ++ii) {
    int q2 = ii * 8 + rr;
    short8 vv = *(const short8*)&ep[q2 * 64 + ((cc ^ (q2 & 7)) << 3)];
    *(short8*)&Ob[(size_t)(q0 + wave * 32 + q2) * DD + cc * 8] = vv;
  }
}

// ---------------- launch ----------------
extern "C" void kernel_launch(void* const* d_in, const int* in_sizes, int n_in,
                              void* d_out, int out_size, void* d_ws, size_t ws_size,
                              hipStream_t stream) {
  const float* qa   = (const float*)d_in[0];
  const float* ma   = (const float*)d_in[1];
  const float* bias = (const float*)d_in[2];
  const float* Wq   = (const float*)d_in[3];
  const float* Wk   = (const float*)d_in[4];
  const float* Wv   = (const float*)d_in[5];
  const float* Wo   = (const float*)d_in[6];
  float* out = (float*)d_out;

  char* ws = (char*)d_ws;
  size_t off = 0;
  auto alloc = [&](size_t bytes) {
    char* p = ws + off;
    off += (bytes + 255) & ~(size_t)255;
    return p;
  };
  const size_t nQKV = (size_t)BB * SS * DD;
  short* qa_bf   = (short*)alloc(nQKV * 2);
  short* ma_bf   = (short*)alloc(nQKV * 2);   // contiguous after qa_bf
  short* bias_bk = (short*)alloc((size_t)BB * SS * SS * 2);
  short* Wqt  = (short*)alloc((size_t)DD * DD * 2);
  short* Wkvt = (short*)alloc((size_t)2 * DD * DD * 2);
  short* Wot  = (short*)alloc((size_t)DD * DD * 2);
  short* Qp   = (short*)alloc(nQKV * 2);
  short* Kp   = (short*)alloc(nQKV * 2);
  short* AOp  = (short*)alloc(nQKV * 2);
  short* VTp  = qa_bf;  // reuse: qa_bf dead after Q-projection GEMM
  (void)ma_bf;

  const float LOG2E = 1.4426950408889634f;
  prep_kernel<<<36864, 256, 0, stream>>>(qa, ma, bias, Wq, Wk, Wv, Wo,
                                         qa_bf, bias_bk, Wqt, Wkvt, Wot,
                                         0.125f * LOG2E, LOG2E);

  gemm_kernel<0, 64><<<BB * SS / 64 * (DD / 128), 256, 0, stream>>>(qa_bf, Wqt, Qp, BB * SS, DD, DD);
  gemm_kv<<<BB * SS / 128 * 16, 256, 0, stream>>>(qa_bf + nQKV, Wkvt, Kp, VTp, DD);

  attn_kernel<<<BB * HH * (SS / 128), 256, 0, stream>>>(Qp, Kp, VTp, bias_bk, AOp, DD);

  gemm_kernel<1, 64><<<BB * SS / 64 * (DD / 128), 256, 0, stream>>>(AOp, Wot, out, BB * SS, DD, DD);
}

// Round 15
// 240.704 us; speedup vs baseline: 1.3402x; 1.0191x over previous
//
#include <hip/hip_runtime.h>
#include <hip/hip_bf16.h>

#define BB 4
#define SS 2048
#define DD 1024
#define HH 16
#define DHH 64

typedef __attribute__((ext_vector_type(8))) short short8;
typedef __attribute__((ext_vector_type(4))) float floatx4;
typedef __attribute__((ext_vector_type(16))) float floatx16;
typedef __attribute__((ext_vector_type(4))) int int4v;

__device__ inline short f2bf(float x) {
  union { float f; unsigned u; } v; v.f = x;
  unsigned r = v.u + 0x7FFFu + ((v.u >> 16) & 1u);
  return (short)(r >> 16);
}
__device__ inline float bf2f(short x) {
  union { unsigned u; float f; } v;
  v.u = ((unsigned)(unsigned short)x) << 16;
  return v.f;
}
__device__ inline int cvtpk(float lo, float hi) {
  int r;
  asm("v_cvt_pk_bf16_f32 %0, %1, %2" : "=v"(r) : "v"(lo), "v"(hi));
  return r;
}
// DST[63:32] <-> SRC[31:0]
__device__ inline void pl32swap(int& a, int& b) {
  asm("v_permlane32_swap_b32 %0, %1" : "+v"(a), "+v"(b));
}

typedef __attribute__((address_space(1))) const unsigned int GUI;
typedef __attribute__((address_space(3))) unsigned int LUI;
__device__ inline void gload16(const void* g, void* l) {
  __builtin_amdgcn_global_load_lds((GUI*)g, (LUI*)l, 16, 0, 0);
}

// ---------------- fused prep: cvt(qa,ma) + wtrans x4 + btrans, one dispatch -----
__global__ __launch_bounds__(256) void prep_kernel(
    const float* __restrict__ qa, const float* __restrict__ ma,
    const float* __restrict__ bias,
    const float* __restrict__ W0, const float* __restrict__ W1,
    const float* __restrict__ W2, const float* __restrict__ W3,
    short* __restrict__ qm_bf, short* __restrict__ bias_bk,
    short* __restrict__ Wqt, short* __restrict__ Wkvt, short* __restrict__ Wot,
    float wqscale, float bscale) {
  __shared__ alignas(16) char smemraw[8704];
  const int blk = blockIdx.x;
  const int t = threadIdx.x;
  if (blk < 16384) {
    int i = blk * 256 + t;
    const int n4half = (BB * SS * DD) / 4;
    const float* src = (i < n4half) ? qa : ma;
    int j = (i < n4half) ? i : i - n4half;
    float4 v = ((const float4*)src)[j];
    short4 o;
    o.x = f2bf(v.x); o.y = f2bf(v.y); o.z = f2bf(v.z); o.w = f2bf(v.w);
    ((short4*)qm_bf)[i] = o;
  } else if (blk < 32768) {
    float(*tile)[17] = (float(*)[17])smemraw;
    int jj = blk - 16384;
    int z = jj >> 12, rem = jj & 4095;
    int by = rem >> 6, bx = rem & 63;
    const float* in = (z == 0) ? W0 : (z == 1) ? W1 : (z == 2) ? W2 : W3;
    short* out = (z == 0) ? Wqt : (z == 1) ? Wkvt
                 : (z == 2) ? (Wkvt + (size_t)DD * DD) : Wot;
    const float scale = (z == 0) ? wqscale : 1.0f;
    int tx = t & 15, ty = t >> 4;
    int k = by * 16 + ty;
    int n = bx * 16 + tx;
    tile[ty][tx] = in[(size_t)k * 1024 + n];
    __syncthreads();
    int n2 = bx * 16 + ty;
    int k2 = by * 16 + tx;
    out[(size_t)n2 * 1024 + k2] = f2bf(tile[tx][ty] * scale);
  } else {
    short(*tile)[68] = (short(*)[68])smemraw;
    int jj = blk - 32768;
    int b = jj >> 10, rem = jj & 1023;
    int by = rem >> 5, bx = rem & 31;
    int q0 = bx * 64, kv0 = by * 64;
    const float* gin = bias + ((size_t)b * SS + q0) * SS + kv0;
#pragma unroll
    for (int i = 0; i < 4; ++i) {
      int idx = t + 256 * i;
      int row = idx >> 4, c4 = idx & 15;
      float4 v = ((const float4*)(gin + (size_t)row * SS))[c4];
      tile[row][c4 * 4 + 0] = f2bf(v.x * bscale);
      tile[row][c4 * 4 + 1] = f2bf(v.y * bscale);
      tile[row][c4 * 4 + 2] = f2bf(v.z * bscale);
      tile[row][c4 * 4 + 3] = f2bf(v.w * bscale);
    }
    __syncthreads();
    short* gout = bias_bk + (size_t)((b * 32 + (kv0 >> 6)) * 16) * 8192 + (size_t)q0 * 4;
#pragma unroll
    for (int i = 0; i < 4; ++i) {
      int idx = t + 256 * i;
      int s = idx >> 6, ql = idx & 63;
      int kvt = s >> 3, g = (s >> 1) & 3, hi = s & 1;
      short4 v = *(const short4*)&tile[ql][kvt * 32 + g * 8 + hi * 4];
      *(short4*)&gout[(size_t)s * 8192 + (size_t)ql * 4] = v;
    }
  }
}

// ---------------- merged Q + KV projection GEMM, one dispatch -------------------
// blocks [0,1024):  Q = qa_bf @ Wqt^T      (TM=64,  N=1024) -> Qp bf16
// blocks [1024,2048): KV = ma_bf @ Wkvt^T  (TM=128, N=2048) -> Kp dense + VT fused
__global__ __launch_bounds__(256) void gemm_qkv(const short* __restrict__ Aq,
                                                const short* __restrict__ Akv,
                                                const short* __restrict__ Wq,
                                                const short* __restrict__ Wkv,
                                                short* __restrict__ Qp,
                                                short* __restrict__ Kp,
                                                short* __restrict__ VT) {
  __shared__ alignas(16) short smem[16384];   // 32KB
  const int t = threadIdx.x;
  const int lane = t & 63, wave = t >> 6;
  const int wr = wave >> 1, wc = wave & 1;
  const int l15 = lane & 15, l4 = lane >> 4;
  const int K = 1024;
  const int o0 = t * 16, o1 = t * 16 + 4096;
  const int r0 = o0 >> 6, r1 = o1 >> 6;
  const int c0 = (((o0 >> 1) & 31) ^ ((r0 & 3) << 3));
  const int c1 = (((o1 >> 1) & 31) ^ ((r1 & 3) << 3));
  const int koff = (l4 ^ (l15 & 3)) * 8;

  if (blockIdx.x < 1024) {
    // ================= Q path: TM=64 =================
    short (*As)[64][32] = (short(*)[64][32])smem;           // 8KB
    short (*Bs)[128][32] = (short(*)[128][32])(smem + 4096); // 16KB
    const int idx = blockIdx.x;
    const int L = (idx & 7) * 128 + (idx >> 3);
    const int bxm = L >> 3, byn = L & 7;

    floatx4 acc[2][4];
#pragma unroll
    for (int i = 0; i < 2; ++i)
#pragma unroll
      for (int j = 0; j < 4; ++j) acc[i][j] = (floatx4){0.f, 0.f, 0.f, 0.f};

    const short* Ag = Aq + (size_t)bxm * 64 * K;
    const short* Bg = Wq + (size_t)byn * 128 * K;
    const int rbase = wr * 32 + l15;
    const int cbase = wc * 64 + l15;

#define QSTAGE(buf, k0)                                                    \
    {                                                                      \
      gload16(&Ag[(size_t)r0 * K + (k0) + c0], (char*)As[buf] + o0);       \
      gload16(&Bg[(size_t)r0 * K + (k0) + c0], (char*)Bs[buf] + o0);       \
      gload16(&Bg[(size_t)r1 * K + (k0) + c1], (char*)Bs[buf] + o1);       \
    }

    QSTAGE(0, 0)
    __syncthreads();
    int cur = 0;
    for (int k0 = 0; k0 < K; k0 += 32) {
      if (k0 + 32 < K) { QSTAGE(cur ^ 1, k0 + 32) }
      short8 af[2], bfr[4];
#pragma unroll
      for (int mi = 0; mi < 2; ++mi) af[mi] = *(const short8*)&As[cur][rbase + mi * 16][koff];
#pragma unroll
      for (int ni = 0; ni < 4; ++ni) bfr[ni] = *(const short8*)&Bs[cur][cbase + ni * 16][koff];
      __builtin_amdgcn_s_setprio(1);
#pragma unroll
      for (int mi = 0; mi < 2; ++mi)
#pragma unroll
        for (int ni = 0; ni < 4; ++ni)
          acc[mi][ni] = __builtin_amdgcn_mfma_f32_16x16x32_bf16(af[mi], bfr[ni], acc[mi][ni], 0, 0, 0);
      __builtin_amdgcn_s_setprio(0);
      __syncthreads();
      cur ^= 1;
    }
#undef QSTAGE

    const int row0 = bxm * 64 + wr * 32 + l4 * 4;
    const int col0 = byn * 128 + wc * 64 + l15;
#pragma unroll
    for (int mi = 0; mi < 2; ++mi)
#pragma unroll
      for (int ni = 0; ni < 4; ++ni)
#pragma unroll
        for (int r = 0; r < 4; ++r)
          Qp[(size_t)(row0 + mi * 16 + r) * 1024 + col0 + ni * 16] = f2bf(acc[mi][ni][r]);
  } else {
    // ================= KV path: TM=128 + fused V^T =================
    short (*As)[128][32] = (short(*)[128][32])smem;          // 16KB
    short (*Bs)[128][32] = (short(*)[128][32])(smem + 8192); // 16KB
    const int idx = blockIdx.x - 1024;
    const int L = (idx & 7) * 128 + (idx >> 3);
    const int bxm = L >> 4, byn = L & 15;

    floatx4 acc[4][4];
#pragma unroll
    for (int i = 0; i < 4; ++i)
#pragma unroll
      for (int j = 0; j < 4; ++j) acc[i][j] = (floatx4){0.f, 0.f, 0.f, 0.f};

    const short* Ag = Akv + (size_t)bxm * 128 * K;
    const short* Bg = Wkv + (size_t)byn * 128 * K;
    const int rbase = wr * 64 + l15;
    const int cbase = wc * 64 + l15;

#define KVSTAGE(buf, k0)                                                   \
    {                                                                      \
      gload16(&Ag[(size_t)r0 * K + (k0) + c0], (char*)As[buf] + o0);       \
      gload16(&Ag[(size_t)r1 * K + (k0) + c1], (char*)As[buf] + o1);       \
      gload16(&Bg[(size_t)r0 * K + (k0) + c0], (char*)Bs[buf] + o0);       \
      gload16(&Bg[(size_t)r1 * K + (k0) + c1], (char*)Bs[buf] + o1);       \
    }

    KVSTAGE(0, 0)
    __syncthreads();
    int cur = 0;
    for (int k0 = 0; k0 < K; k0 += 32) {
      if (k0 + 32 < K) { KVSTAGE(cur ^ 1, k0 + 32) }
      short8 af[4], bfr[4];
#pragma unroll
      for (int mi = 0; mi < 4; ++mi) af[mi] = *(const short8*)&As[cur][rbase + mi * 16][koff];
#pragma unroll
      for (int ni = 0; ni < 4; ++ni) bfr[ni] = *(const short8*)&Bs[cur][cbase + ni * 16][koff];
      __builtin_amdgcn_s_setprio(1);
#pragma unroll
      for (int mi = 0; mi < 4; ++mi)
#pragma unroll
        for (int ni = 0; ni < 4; ++ni)
          acc[mi][ni] = __builtin_amdgcn_mfma_f32_16x16x32_bf16(af[mi], bfr[ni], acc[mi][ni], 0, 0, 0);
      __builtin_amdgcn_s_setprio(0);
      __syncthreads();
      cur ^= 1;
    }
#undef KVSTAGE

    if (byn < 8) {
      const int row0 = bxm * 128 + wr * 64 + l4 * 4;
      const int col0 = byn * 128 + wc * 64 + l15;
#pragma unroll
      for (int mi = 0; mi < 4; ++mi)
#pragma unroll
        for (int ni = 0; ni < 4; ++ni)
#pragma unroll
          for (int r = 0; r < 4; ++r)
            Kp[(size_t)(row0 + mi * 16 + r) * 1024 + col0 + ni * 16] = f2bf(acc[mi][ni][r]);
    } else {
      // V half: transpose via LDS, store VT[b][d][s]
      short* tl = smem;
#pragma unroll
      for (int mi = 0; mi < 4; ++mi)
#pragma unroll
        for (int ni = 0; ni < 4; ++ni)
#pragma unroll
          for (int r = 0; r < 4; ++r) {
            int srow = wr * 64 + mi * 16 + l4 * 4 + r;
            int dcol = wc * 64 + ni * 16 + l15;
            tl[dcol * 128 + (srow ^ ((dcol & 7) << 3))] = f2bf(acc[mi][ni][r]);
          }
      __syncthreads();
      const int b = bxm >> 4;
      const int s0 = (bxm & 15) * 128;
      const int d0 = (byn - 8) * 128;
      short* Vb = VT + ((size_t)b * DD + d0) * SS + s0;
#pragma unroll
      for (int i = 0; i < 8; ++i) {
        int ci = t + 256 * i;
        int dr = ci >> 4, c = ci & 15;
        short8 v = *(const short8*)&tl[dr * 128 + ((c ^ (dr & 7)) << 3)];
        *(short8*)&Vb[(size_t)dr * SS + c * 8] = v;
      }
    }
  }
}

// ---------------- O projection GEMM (TM=64, f32 out) ---------------------------
template<int OUT_F32, int TM>
__global__ __launch_bounds__(256) void gemm_kernel(const short* __restrict__ A,
                                                   const short* __restrict__ Bt,
                                                   void* __restrict__ Cout,
                                                   int M, int N, int K) {
  constexpr int MI = TM / 32;
  __shared__ alignas(16) short As[2][TM][32];
  __shared__ alignas(16) short Bs[2][128][32];
  const int t = threadIdx.x;
  const int lane = t & 63, wave = t >> 6;
  const int wr = wave >> 1, wc = wave & 1;
  const int l15 = lane & 15, l4 = lane >> 4;

  const int hw = blockIdx.x;
  const int L = (hw & 7) * ((int)gridDim.x >> 3) + (hw >> 3);
  const int NY = N >> 7;
  const int bxm = L / NY, byn = L % NY;

  floatx4 acc[MI][4];
#pragma unroll
  for (int i = 0; i < MI; ++i)
#pragma unroll
    for (int j = 0; j < 4; ++j) acc[i][j] = (floatx4){0.f, 0.f, 0.f, 0.f};

  const short* Ag = A + (size_t)bxm * TM * K;
  const short* Bg = Bt + (size_t)byn * 128 * K;
  const int o0 = t * 16, o1 = t * 16 + 4096;
  const int r0 = o0 >> 6, r1 = o1 >> 6;
  const int c0 = (((o0 >> 1) & 31) ^ ((r0 & 3) << 3));
  const int c1 = (((o1 >> 1) & 31) ^ ((r1 & 3) << 3));
  const int rbase = wr * (TM / 2) + l15;
  const int cbase = wc * 64 + l15;
  const int koff = (l4 ^ (l15 & 3)) * 8;

#define GSTAGE(buf, k0)                                                    \
  {                                                                        \
    gload16(&Ag[(size_t)r0 * K + (k0) + c0], (char*)As[buf] + o0);         \
    if (TM == 128)                                                         \
      gload16(&Ag[(size_t)r1 * K + (k0) + c1], (char*)As[buf] + o1);       \
    gload16(&Bg[(size_t)r0 * K + (k0) + c0], (char*)Bs[buf] + o0);         \
    gload16(&Bg[(size_t)r1 * K + (k0) + c1], (char*)Bs[buf] + o1);         \
  }

  GSTAGE(0, 0)
  __syncthreads();
  int cur = 0;
  for (int k0 = 0; k0 < K; k0 += 32) {
    if (k0 + 32 < K) { GSTAGE(cur ^ 1, k0 + 32) }
    short8 af[MI], bfr[4];
#pragma unroll
    for (int mi = 0; mi < MI; ++mi) af[mi] = *(const short8*)&As[cur][rbase + mi * 16][koff];
#pragma unroll
    for (int ni = 0; ni < 4; ++ni) bfr[ni] = *(const short8*)&Bs[cur][cbase + ni * 16][koff];
    __builtin_amdgcn_s_setprio(1);
#pragma unroll
    for (int mi = 0; mi < MI; ++mi)
#pragma unroll
      for (int ni = 0; ni < 4; ++ni)
        acc[mi][ni] = __builtin_amdgcn_mfma_f32_16x16x32_bf16(af[mi], bfr[ni], acc[mi][ni], 0, 0, 0);
    __builtin_amdgcn_s_setprio(0);
    __syncthreads();
    cur ^= 1;
  }
#undef GSTAGE

  const int row0 = bxm * TM + wr * (TM / 2) + l4 * 4;
  const int col0 = byn * 128 + wc * 64 + l15;
  if (OUT_F32) {
    float* Cf = (float*)Cout;
#pragma unroll
    for (int mi = 0; mi < MI; ++mi)
#pragma unroll
      for (int ni = 0; ni < 4; ++ni)
#pragma unroll
        for (int r = 0; r < 4; ++r)
          Cf[(size_t)(row0 + mi * 16 + r) * N + col0 + ni * 16] = acc[mi][ni][r];
  } else {
    short* Cs = (short*)Cout;
#pragma unroll
    for (int mi = 0; mi < MI; ++mi)
#pragma unroll
      for (int ni = 0; ni < 4; ++ni)
#pragma unroll
        for (int r = 0; r < 4; ++r)
          Cs[(size_t)(row0 + mi * 16 + r) * N + col0 + ni * 16] = f2bf(acc[mi][ni][r]);
  }
}

// ---------------- flash attention: no-max log2 softmax, VALU row-sum -----------
// (unchanged: 107 us, 96 total regs, 4 waves/SIMD)
__global__ __launch_bounds__(256, 4) void attn_kernel(const short* __restrict__ Q,
                                                      const short* __restrict__ K,
                                                      const short* __restrict__ VT,
                                                      const short* __restrict__ bias_blk,
                                                      short* __restrict__ O, int ldk) {
  __shared__ alignas(16) short Klds[2][64][64];      // 16KB
  __shared__ alignas(16) short Vtl[2][64][64];       // 16KB

  const int t = threadIdx.x;
  const int lane = t & 63, wave = t >> 6;
  const int hw = blockIdx.x;
  const int L = (hw & 7) * 128 + (hw >> 3);
  const int bh = L >> 4;
  const int q0 = (L & 15) * 128;
  const int b = bh >> 4, h = bh & 15;
  const int l31 = lane & 31, hi = lane >> 5;

  const short* Qb = Q + (size_t)b * SS * DD + h * DHH;
  const short* Kb = K + (size_t)b * SS * ldk + h * DHH;
  const short* VTb = VT + ((size_t)b * DD + h * DHH) * SS;
  const short* Bl = bias_blk + (size_t)(b * 32 * 16) * 8192 + (size_t)hi * 8192
                    + (size_t)(q0 + wave * 32 + l31) * 4;

  const int sr0 = t >> 3;
  const int scb = ((t & 7) ^ (sr0 & 7)) * 8;

#define STAGE_KV(buf, kvb)                                                              \
  {                                                                                     \
    gload16(&Kb[(size_t)((kvb) + sr0) * ldk + scb], (char*)&Klds[buf][0][0] + t * 16);  \
    gload16(&Kb[(size_t)((kvb) + sr0 + 32) * ldk + scb],                                \
            (char*)&Klds[buf][0][0] + 4096 + t * 16);                                   \
    gload16(&VTb[(size_t)sr0 * SS + (kvb) + scb], (char*)&Vtl[buf][0][0] + t * 16);     \
    gload16(&VTb[(size_t)(sr0 + 32) * SS + (kvb) + scb],                                \
            (char*)&Vtl[buf][0][0] + 4096 + t * 16);                                    \
  }
#define BIAS_PREF(kvb)                                                                  \
  {                                                                                     \
    int kt16 = ((kvb) >> 6) << 4;                                                       \
    _Pragma("unroll")                                                                   \
    for (int kvt = 0; kvt < 2; ++kvt)                                                   \
      _Pragma("unroll")                                                                 \
      for (int g = 0; g < 4; ++g)                                                       \
        br[kvt * 4 + g] = *(const short4*)&Bl[(size_t)(kt16 + kvt * 8 + g * 2) * 8192]; \
  }

  short4 br[8];
  STAGE_KV(0, 0)
  BIAS_PREF(0)

  const int q = wave * 32 + l31;
  short8 qf[4];
  {
    int qrow = q0 + q;
#pragma unroll
    for (int dc = 0; dc < 4; ++dc)
      qf[dc] = *(const short8*)&Qb[(size_t)qrow * DD + dc * 16 + hi * 8];
  }

  floatx16 acc_pv[2];
#pragma unroll
  for (int r = 0; r < 16; ++r) { acc_pv[0][r] = 0.f; acc_pv[1][r] = 0.f; }
  float psum = 0.f;

  __syncthreads();
  int cur = 0;
  for (int kv0 = 0; kv0 < SS; kv0 += 64) {
    if (kv0 + 64 < SS) STAGE_KV(cur ^ 1, kv0 + 64)

#pragma unroll
    for (int kvt = 0; kvt < 2; ++kvt) {
      floatx16 c_;
#pragma unroll
      for (int g = 0; g < 4; ++g) {
        short4 b4 = br[kvt * 4 + g];
        c_[4 * g + 0] = bf2f(b4.x); c_[4 * g + 1] = bf2f(b4.y);
        c_[4 * g + 2] = bf2f(b4.z); c_[4 * g + 3] = bf2f(b4.w);
      }
      int kr = kvt * 32 + l31;
      __builtin_amdgcn_s_setprio(1);
#pragma unroll
      for (int dc = 0; dc < 4; ++dc) {
        short8 kf = *(const short8*)&Klds[cur][kr][((2 * dc + hi) ^ (kr & 7)) * 8];
        c_ = __builtin_amdgcn_mfma_f32_32x32x16_bf16(kf, qf[dc], c_, 0, 0, 0);
      }
      __builtin_amdgcn_s_setprio(0);

      if (kvt == 1 && kv0 + 64 < SS) BIAS_PREF(kv0 + 64)

      int dd[8];
#pragma unroll
      for (int i = 0; i < 8; ++i) {
        float e0 = __builtin_amdgcn_exp2f(c_[2 * i]);
        float e1 = __builtin_amdgcn_exp2f(c_[2 * i + 1]);
        psum += e0 + e1;
        dd[i] = cvtpk(e0, e1);
      }

#pragma unroll
      for (int ks2 = 0; ks2 < 2; ++ks2) {
        int a0 = dd[4 * ks2 + 0], a1 = dd[4 * ks2 + 1];
        int a2 = dd[4 * ks2 + 2], a3 = dd[4 * ks2 + 3];
        pl32swap(a0, a2);
        pl32swap(a1, a3);
        int4v w; w[0] = a0; w[1] = a1; w[2] = a2; w[3] = a3;
        short8 pf = *(short8*)&w;
        int ks = kvt * 2 + ks2;
        __builtin_amdgcn_s_setprio(1);
#pragma unroll
        for (int dt = 0; dt < 2; ++dt) {
          int vr = dt * 32 + l31;
          short8 vf = *(const short8*)&Vtl[cur][vr][((2 * ks + hi) ^ (vr & 7)) * 8];
          acc_pv[dt] = __builtin_amdgcn_mfma_f32_32x32x16_bf16(vf, pf, acc_pv[dt], 0, 0, 0);
        }
        __builtin_amdgcn_s_setprio(0);
      }
    }
    __syncthreads();
    cur ^= 1;
  }
#undef STAGE_KV
#undef BIAS_PREF

  float ssum = psum + __shfl_xor(psum, 32);
  float inv = 1.0f / ssum;

  short* ep = (short*)Klds + wave * 2048;
#pragma unroll
  for (int dt = 0; dt < 2; ++dt)
#pragma unroll
    for (int r = 0; r < 16; ++r) {
      int d = dt * 32 + (r & 3) + 8 * (r >> 2) + 4 * hi;
      int chunk = d >> 3, doff = d & 7;
      ep[l31 * 64 + ((chunk ^ (l31 & 7)) << 3) + doff] = f2bf(acc_pv[dt][r] * inv);
    }
  short* Ob = O + (size_t)b * SS * DD + h * DHH;
  const int rr = lane >> 3, cc = lane & 7;
#pragma unroll
  for (int ii = 0; ii < 4; ++ii) {
    int q2 = ii * 8 + rr;
    short8 vv = *(const short8*)&ep[q2 * 64 + ((cc ^ (q2 & 7)) << 3)];
    *(short8*)&Ob[(size_t)(q0 + wave * 32 + q2) * DD + cc * 8] = vv;
  }
}

// ---------------- launch ----------------
extern "C" void kernel_launch(void* const* d_in, const int* in_sizes, int n_in,
                              void* d_out, int out_size, void* d_ws, size_t ws_size,
                              hipStream_t stream) {
  const float* qa   = (const float*)d_in[0];
  const float* ma   = (const float*)d_in[1];
  const float* bias = (const float*)d_in[2];
  const float* Wq   = (const float*)d_in[3];
  const float* Wk   = (const float*)d_in[4];
  const float* Wv   = (const float*)d_in[5];
  const float* Wo   = (const float*)d_in[6];
  float* out = (float*)d_out;

  char* ws = (char*)d_ws;
  size_t off = 0;
  auto alloc = [&](size_t bytes) {
    char* p = ws + off;
    off += (bytes + 255) & ~(size_t)255;
    return p;
  };
  const size_t nQKV = (size_t)BB * SS * DD;
  short* qa_bf   = (short*)alloc(nQKV * 2);
  short* ma_bf   = (short*)alloc(nQKV * 2);   // contiguous after qa_bf
  short* bias_bk = (short*)alloc((size_t)BB * SS * SS * 2);
  short* Wqt  = (short*)alloc((size_t)DD * DD * 2);
  short* Wkvt = (short*)alloc((size_t)2 * DD * DD * 2);
  short* Wot  = (short*)alloc((size_t)DD * DD * 2);
  short* Qp   = (short*)alloc(nQKV * 2);
  short* Kp   = (short*)alloc(nQKV * 2);
  short* VTp  = (short*)alloc(nQKV * 2);   // separate: Q-blocks read qa_bf concurrently
  short* AOp  = (short*)alloc(nQKV * 2);

  const float LOG2E = 1.4426950408889634f;
  prep_kernel<<<36864, 256, 0, stream>>>(qa, ma, bias, Wq, Wk, Wv, Wo,
                                         qa_bf, bias_bk, Wqt, Wkvt, Wot,
                                         0.125f * LOG2E, LOG2E);

  gemm_qkv<<<2048, 256, 0, stream>>>(qa_bf, ma_bf, Wqt, Wkvt, Qp, Kp, VTp);

  attn_kernel<<<BB * HH * (SS / 128), 256, 0, stream>>>(Qp, Kp, VTp, bias_bk, AOp, DD);

  gemm_kernel<1, 64><<<BB * SS / 64 * (DD / 128), 256, 0, stream>>>(AOp, Wot, out, BB * SS, DD, DD);
}